// Round 15
// baseline (488.864 us; speedup 1.0000x reference)
//
#include <hip/hip_runtime.h>

typedef unsigned int   u32;
typedef unsigned short u16;
typedef __bf16 bf16x8 __attribute__((ext_vector_type(8)));
typedef float  f32x4  __attribute__((ext_vector_type(4)));

__device__ __forceinline__ u16 f2bf(float f) {
    u32 u = __builtin_bit_cast(u32, f);
    u += 0x7FFFu + ((u >> 16) & 1u);
    return (u16)(u >> 16);
}
// packed f32x2 -> bf16x2 (RNE), single instruction
__device__ __forceinline__ u32 cvtpk(float a, float b) {
    u32 r;
    asm("v_cvt_pk_bf16_f32 %0, %1, %2" : "=v"(r) : "v"(a), "v"(b));
    return r;
}
__device__ __forceinline__ bf16x8 ldfrag(const u16* p) {
    return __builtin_bit_cast(bf16x8, *reinterpret_cast<const uint4*>(p));
}

// bank-conflict swizzle on the 16B-chunk index (0..63): fold bits[5:3] into [2:0].
__device__ __forceinline__ u32 swz(u32 i) { return i ^ ((i >> 3) & 7u); }

// ---------------------------------------------------------------------------
// Fused Swin branch, R15 = R12's swapped dataflow with PHASE-STAGGERED halves.
// WG = 768 threads = two 6-wave halves, each owning an independent window
// stream (4 windows each; persistent, grid 256). Phases per window:
//   P0 gather+partial-LN-sums (HBM)   P1 LN->yln (VALU/LDS)
//   P2 QKV GEMM (MFMA)                P3 attention (MFMA/VALU)
//   P4 proj + residual + store (MFMA+HBM)
// win1 runs 2 barrier-intervals BEHIND win0, so each interval pairs a
// memory-heavy phase of one half with a compute-heavy phase of the other
// ((P2,P0),(P3,P1),(P4,P2),(P0,P3),(P1,P4) in steady state) -> the CU
// overlaps HBM and MFMA work that R12's phase-locked WG serialized.
// Barriers are WG-wide rendezvous (wave-uniform branching; equal count both
// halves). Cross-interval reg state: xv[32] (P0->P1), kpk/vpk (P2->P3).
// Per-half LDS (u16, base=win*24576): [0,12288) yln 24 frag blocks (P3: wave
// w's blocks {s*6+w} = K scratch -> P(ks=1) -> O^T); [12288,24576) qreg.
// ---------------------------------------------------------------------------
template<int SHIFT>
__global__ __launch_bounds__(768) void swin_branch(
    const float* __restrict__ xin, float* __restrict__ xout,
    const float* __restrict__ ln_g, const float* __restrict__ ln_b,
    const u16*   __restrict__ wqkv_t,  // [576][192] bf16 (pre-transposed)
    const float* __restrict__ qkv_b,   // [576]
    const u16*   __restrict__ wproj_t, // [192][192] bf16 (pre-transposed)
    const float* __restrict__ proj_b)  // [192]
{
    __shared__ __align__(16) u16 smem[49152];
    __shared__ float red1[2][6][64];
    __shared__ float red2[2][6][64];
    constexpr u32 QOFF = 12288;
    constexpr float QSC = 0.17677669529663689f * 1.4426950408889634f; // 1/sqrt(32)*log2(e)

    const int tid  = threadIdx.x;
    const int win  = (tid >= 384) ? 1 : 0;
    const int lt   = tid - win*384;
    const int wid  = lt >> 6;               // wave == head
    const int lane = lt & 63;
    const int lr   = lane & 15;
    const int lg   = lane >> 4;
    const u32 lsw  = swz((u32)lane);
    const u32 SB   = (u32)win * 24576u;
    const int ty   = lane >> 3, tx = lane & 7;

    // cross-interval register state
    float xv[32];            // P0 -> P1
    uint2 kpk[4][2];         // P2 -> P3
    uint2 vpk[4][2];         // P2 -> P3
    int b = 0, wy = 0, wx = 0;

    #pragma unroll 1
    for (int t = 0; t < 22; ++t) {
        const int ph = t - 2*win;
        if (ph >= 0 && ph < 20) {
            const int widx = ph / 5;
            const int p    = ph - widx*5;

            if (p == 0) {
                // ---- P0: window coords, gather x (rolled), partial LN sums ----
                const int Wid = (widx*256 + (int)blockIdx.x)*2 + win;
                b = Wid >> 8; wy = (Wid >> 4) & 15; wx = Wid & 15;
                const int shy = (wy*8 + ty + SHIFT) & 127;
                const int shx = (wx*8 + tx + SHIFT) & 127;
                const float* xp = xin + ((size_t)((b*128 + shy)*128 + shx))*192 + wid*32;
                float s1 = 0.f, s2 = 0.f;
                #pragma unroll
                for (int j = 0; j < 8; ++j) {
                    float4 v = reinterpret_cast<const float4*>(xp)[j];
                    xv[j*4+0]=v.x; xv[j*4+1]=v.y; xv[j*4+2]=v.z; xv[j*4+3]=v.w;
                    s1 += v.x+v.y+v.z+v.w;
                    s2 += v.x*v.x + v.y*v.y + v.z*v.z + v.w*v.w;
                }
                red1[win][wid][lane] = s1; red2[win][wid][lane] = s2;

            } else if (p == 1) {
                // ---- P1: finish LN, write yln (frag layout) ----
                float a1 = 0.f, a2 = 0.f;
                #pragma unroll
                for (int w = 0; w < 6; ++w) { a1 += red1[win][w][lane]; a2 += red2[win][w][lane]; }
                const float mu = a1 * (1.f/192.f);
                const float rs = rsqrtf(a2 * (1.f/192.f) - mu*mu + 1e-5f);
                const float* gp = ln_g + wid*32;
                const float* bp = ln_b + wid*32;
                const u32 yblk = SB + (u32)((lg*6 + wid)*512);
                #pragma unroll
                for (int cc8 = 0; cc8 < 4; ++cc8) {
                    u32 pk[4];
                    #pragma unroll
                    for (int q = 0; q < 4; ++q) {
                        int j = cc8*8 + q*2;
                        float y0 = (xv[j]   - mu)*rs*gp[j]   + bp[j];
                        float y1 = (xv[j+1] - mu)*rs*gp[j+1] + bp[j+1];
                        pk[q] = cvtpk(y0, y1);
                    }
                    *reinterpret_cast<uint4*>(&smem[yblk + swz((u32)(lr + 16*cc8))*8]) =
                        make_uint4(pk[0],pk[1],pk[2],pk[3]);
                }

            } else if (p == 2) {
                // ---- P2: QKV GEMM (pass1 swapped q+k; pass2 v) ----
                {
                    f32x4 acc[4][4];
                    #pragma unroll
                    for (int mi=0; mi<4; ++mi)
                        #pragma unroll
                        for (int q=0; q<4; ++q) acc[mi][q] = f32x4{0.f,0.f,0.f,0.f};
                    #pragma unroll
                    for (int ks=0; ks<6; ++ks) {
                        bf16x8 af[4];
                        #pragma unroll
                        for (int mi=0; mi<4; ++mi)
                            af[mi] = ldfrag(&smem[SB + (u32)((mi*6+ks)*512) + lsw*8]);
                        bf16x8 bw[4];
                        #pragma unroll
                        for (int q=0; q<4; ++q)
                            bw[q] = ldfrag(&wqkv_t[((q>>1)*192 + wid*32 + (q&1)*16 + lr)*192 + 32*ks + 8*lg]);
                        #pragma unroll
                        for (int mi=0; mi<4; ++mi)
                            #pragma unroll
                            for (int q=0; q<4; ++q)
                                acc[mi][q] = __builtin_amdgcn_mfma_f32_16x16x32_bf16(bw[q], af[mi], acc[mi][q], 0,0,0);
                    }
                    #pragma unroll
                    for (int q=0; q<2; ++q) {
                        const float4 b4 = *reinterpret_cast<const float4*>(&qkv_b[wid*32 + q*16 + 4*lg]);
                        const u32 chunk = (u32)lr + 16u*(u32)(2*q + (lg>>1));
                        #pragma unroll
                        for (int mi=0; mi<4; ++mi) {
                            float v0 = (acc[mi][q][0] + b4.x) * QSC;
                            float v1 = (acc[mi][q][1] + b4.y) * QSC;
                            float v2 = (acc[mi][q][2] + b4.z) * QSC;
                            float v3 = (acc[mi][q][3] + b4.w) * QSC;
                            *reinterpret_cast<uint2*>(
                                &smem[SB + QOFF + (u32)(wid*2048) + mi*512 + swz(chunk)*8 + 4*(lg&1)]) =
                                make_uint2(cvtpk(v0,v1), cvtpk(v2,v3));
                        }
                    }
                    #pragma unroll
                    for (int t2=0; t2<2; ++t2) {
                        const float4 b4 = *reinterpret_cast<const float4*>(&qkv_b[192 + wid*32 + t2*16 + 4*lg]);
                        #pragma unroll
                        for (int mi=0; mi<4; ++mi)
                            kpk[mi][t2] = make_uint2(
                                cvtpk(acc[mi][2+t2][0] + b4.x, acc[mi][2+t2][1] + b4.y),
                                cvtpk(acc[mi][2+t2][2] + b4.z, acc[mi][2+t2][3] + b4.w));
                    }
                }
                {
                    f32x4 acc[4][2];
                    #pragma unroll
                    for (int mi=0; mi<4; ++mi)
                        #pragma unroll
                        for (int q=0; q<2; ++q) acc[mi][q] = f32x4{0.f,0.f,0.f,0.f};
                    #pragma unroll
                    for (int ks=0; ks<6; ++ks) {
                        bf16x8 af[4];
                        #pragma unroll
                        for (int mi=0; mi<4; ++mi)
                            af[mi] = ldfrag(&smem[SB + (u32)((mi*6+ks)*512) + lsw*8]);
                        bf16x8 bw[2];
                        #pragma unroll
                        for (int q=0; q<2; ++q)
                            bw[q] = ldfrag(&wqkv_t[(384 + wid*32 + q*16 + lr)*192 + 32*ks + 8*lg]);
                        #pragma unroll
                        for (int mi=0; mi<4; ++mi)
                            #pragma unroll
                            for (int q=0; q<2; ++q)
                                acc[mi][q] = __builtin_amdgcn_mfma_f32_16x16x32_bf16(af[mi], bw[q], acc[mi][q], 0,0,0);
                    }
                    #pragma unroll
                    for (int tv=0; tv<2; ++tv) {
                        const float bias = qkv_b[384 + wid*32 + tv*16 + lr];
                        #pragma unroll
                        for (int mi=0; mi<4; ++mi)
                            vpk[mi][tv] = make_uint2(
                                cvtpk(acc[mi][tv][0] + bias, acc[mi][tv][1] + bias),
                                cvtpk(acc[mi][tv][2] + bias, acc[mi][tv][3] + bias));
                    }
                }

            } else if (p == 3) {
                // ---- P3: attention (all-swapped, wave-local) ----
                float rsum[4];
                f32x4 o_[2][4];
                const u32 W  = SB + (u32)(wid*512);
                const u32 QB = SB + QOFF + (u32)(wid*2048);
                #define BLK(s) ((u32)(s)*3072u + W)

                #pragma unroll
                for (int t2=0; t2<2; ++t2) {
                    const u32 chunk = (u32)lr + 16u*(u32)(2*t2 + (lg>>1));
                    #pragma unroll
                    for (int mi=0; mi<4; ++mi)
                        *reinterpret_cast<uint2*>(
                            &smem[BLK(mi) + swz(chunk)*8 + 4*(lg&1)]) = kpk[mi][t2];
                }
                bf16x8 ak[4], bq[4];
                #pragma unroll
                for (int mi=0; mi<4; ++mi) ak[mi] = ldfrag(&smem[BLK(mi) + lsw*8]);
                #pragma unroll
                for (int nq=0; nq<4; ++nq) bq[nq] = ldfrag(&smem[QB + nq*512 + lsw*8]);
                __builtin_amdgcn_sched_barrier(0);

                int qcl[4];
                if constexpr (SHIFT > 0) {
                    #pragma unroll
                    for (int nq=0; nq<4; ++nq) {
                        const int qt = 16*nq + lr;
                        const int hu = wy*8 + (qt>>3);
                        const int wu = wx*8 + (qt&7);
                        qcl[nq] = ((hu >= 124) ? 2 : (hu >= 120 ? 1 : 0))*3
                                + ((wu >= 124) ? 2 : (wu >= 120 ? 1 : 0));
                    }
                }

                uint2 p16[4][4];
                #pragma unroll
                for (int mi=0; mi<4; ++mi) {
                    f32x4 sr[4];
                    #pragma unroll
                    for (int nq=0; nq<4; ++nq)
                        sr[nq] = __builtin_amdgcn_mfma_f32_16x16x32_bf16(ak[mi], bq[nq],
                                     f32x4{0.f,0.f,0.f,0.f}, 0,0,0);
                    #pragma unroll
                    for (int rg=0; rg<4; ++rg) {
                        int kcl = 0;
                        if constexpr (SHIFT > 0) {
                            const int kt = 16*mi + 4*lg + rg;
                            const int hu = wy*8 + (kt>>3);
                            const int wu = wx*8 + (kt&7);
                            kcl = ((hu >= 124) ? 2 : (hu >= 120 ? 1 : 0))*3
                                + ((wu >= 124) ? 2 : (wu >= 120 ? 1 : 0));
                        }
                        #pragma unroll
                        for (int nq=0; nq<4; ++nq) {
                            float e = exp2f(sr[nq][rg]);
                            if constexpr (SHIFT > 0)
                                e = (kcl == qcl[nq]) ? e : 0.f;
                            sr[nq][rg] = e;
                        }
                    }
                    #pragma unroll
                    for (int nq=0; nq<4; ++nq)
                        p16[mi][nq] = make_uint2(cvtpk(sr[nq][0], sr[nq][1]),
                                                 cvtpk(sr[nq][2], sr[nq][3]));
                }

                #pragma unroll
                for (int mi=0; mi<4; ++mi) {
                    const u32 chunk = (u32)lr + 16u*(u32)(2*(mi&1) + (lg>>1));
                    #pragma unroll
                    for (int nq=0; nq<4; ++nq) {
                        const u32 base = (mi >> 1) ? BLK(nq) : (QB + nq*512);
                        *reinterpret_cast<uint2*>(&smem[base + swz(chunk)*8 + 4*(lg&1)]) = p16[mi][nq];
                    }
                }
                bf16x8 bp[4][2];
                #pragma unroll
                for (int nq=0; nq<4; ++nq) {
                    bp[nq][0] = ldfrag(&smem[QB + nq*512 + lsw*8]);
                    bp[nq][1] = ldfrag(&smem[BLK(nq) + lsw*8]);
                }
                __builtin_amdgcn_sched_barrier(0);

                bf16x8 aones;
                {
                    const u32 one2 = 0x3F803F80u;
                    aones = __builtin_bit_cast(bf16x8, make_uint4(one2, one2, one2, one2));
                }
                #pragma unroll
                for (int nq=0; nq<4; ++nq) {
                    f32x4 racc = __builtin_amdgcn_mfma_f32_16x16x32_bf16(aones, bp[nq][0],
                                     f32x4{0.f,0.f,0.f,0.f}, 0,0,0);
                    racc = __builtin_amdgcn_mfma_f32_16x16x32_bf16(aones, bp[nq][1], racc, 0,0,0);
                    rsum[nq] = __builtin_amdgcn_rcpf(racc[0]);
                }

                #pragma unroll
                for (int mi=0; mi<4; ++mi) {
                    const u32 chunk = (u32)lr + 16u*(u32)(2*(mi&1) + (lg>>1));
                    #pragma unroll
                    for (int tv=0; tv<2; ++tv)
                        *reinterpret_cast<uint2*>(
                            &smem[QB + (u32)((2*tv + (mi>>1))*512) + swz(chunk)*8 + 4*(lg&1)]) = vpk[mi][tv];
                }
                bf16x8 av[2][2];
                #pragma unroll
                for (int dv=0; dv<2; ++dv)
                    #pragma unroll
                    for (int ks=0; ks<2; ++ks)
                        av[dv][ks] = ldfrag(&smem[QB + (u32)((2*dv + ks)*512) + lsw*8]);
                __builtin_amdgcn_sched_barrier(0);

                #pragma unroll
                for (int dv=0; dv<2; ++dv)
                    #pragma unroll
                    for (int nq=0; nq<4; ++nq) {
                        o_[dv][nq] = __builtin_amdgcn_mfma_f32_16x16x32_bf16(av[dv][0], bp[nq][0],
                                         f32x4{0.f,0.f,0.f,0.f}, 0,0,0);
                        o_[dv][nq] = __builtin_amdgcn_mfma_f32_16x16x32_bf16(av[dv][1], bp[nq][1],
                                         o_[dv][nq], 0,0,0);
                    }
                __builtin_amdgcn_sched_barrier(0);

                #pragma unroll
                for (int dv=0; dv<2; ++dv) {
                    const u32 chunk = (u32)lr + 16u*(u32)(2*dv + (lg>>1));
                    #pragma unroll
                    for (int nq=0; nq<4; ++nq) {
                        const float r = rsum[nq];
                        *reinterpret_cast<uint2*>(&smem[BLK(nq) + swz(chunk)*8 + 4*(lg&1)]) =
                            make_uint2(cvtpk(o_[dv][nq][0]*r, o_[dv][nq][1]*r),
                                       cvtpk(o_[dv][nq][2]*r, o_[dv][nq][3]*r));
                    }
                }
                #undef BLK

            } else {
                // ---- P4: proj GEMM + bias + residual + store ----
                f32x4 a2[4][2];
                #pragma unroll
                for (int mi=0; mi<4; ++mi)
                    #pragma unroll
                    for (int ni=0; ni<2; ++ni) a2[mi][ni] = f32x4{0.f,0.f,0.f,0.f};
                #pragma unroll
                for (int ks=0; ks<6; ++ks) {
                    bf16x8 af[4], bw[2];
                    #pragma unroll
                    for (int mi=0; mi<4; ++mi)
                        af[mi] = ldfrag(&smem[SB + (u32)((mi*6+ks)*512) + lsw*8]);
                    #pragma unroll
                    for (int ni=0; ni<2; ++ni)
                        bw[ni] = ldfrag(&wproj_t[(wid*32 + 16*ni + lr)*192 + 32*ks + 8*lg]);
                    #pragma unroll
                    for (int mi=0; mi<4; ++mi)
                        #pragma unroll
                        for (int ni=0; ni<2; ++ni)
                            a2[mi][ni] = __builtin_amdgcn_mfma_f32_16x16x32_bf16(af[mi], bw[ni], a2[mi][ni], 0,0,0);
                }
                #pragma unroll
                for (int ni=0; ni<2; ++ni) {
                    const int c  = wid*32 + 16*ni + lr;
                    const float pb = proj_b[c];
                    #pragma unroll
                    for (int mi=0; mi<4; ++mi)
                        #pragma unroll
                        for (int rg=0; rg<4; ++rg) {
                            const int row = 16*mi + 4*lg + rg;
                            const int ty2 = row >> 3, tx2 = row & 7;
                            const int shy = (wy*8 + ty2 + SHIFT) & 127;
                            const int shx = (wx*8 + tx2 + SHIFT) & 127;
                            const size_t idx = ((size_t)((b*128 + shy)*128 + shx))*192 + c;
                            xout[idx] = xin[idx] + a2[mi][ni][rg] + pb;
                        }
                }
            }
        }
        __syncthreads();
    }
}

// ws layout (u16): [0) wqkv1_t 110592 | 110592) wproj1_t 36864 | 147456) wqkv2_t 110592 | 258048) wproj2_t 36864
__global__ void prep_weights(const float* __restrict__ qkv1, const float* __restrict__ proj1,
                             const float* __restrict__ qkv2, const float* __restrict__ proj2,
                             u16* __restrict__ ws)
{
    const int i = blockIdx.x*blockDim.x + threadIdx.x;
    if (i < 110592) {
        const int n = i / 192, k = i - n*192;
        ws[i]          = f2bf(qkv1[k*576 + n]);
        ws[147456 + i] = f2bf(qkv2[k*576 + n]);
    }
    if (i < 36864) {
        const int n = i / 192, k = i - n*192;
        ws[110592 + i] = f2bf(proj1[k*192 + n]);
        ws[258048 + i] = f2bf(proj2[k*192 + n]);
    }
}

extern "C" void kernel_launch(void* const* d_in, const int* in_sizes, int n_in,
                              void* d_out, int out_size, void* d_ws, size_t ws_size,
                              hipStream_t stream)
{
    const float* x       = (const float*)d_in[0];
    const float* ln1_g   = (const float*)d_in[1];
    const float* ln1_b   = (const float*)d_in[2];
    const float* qkv1_w  = (const float*)d_in[3];
    const float* qkv1_b  = (const float*)d_in[4];
    const float* proj1_w = (const float*)d_in[5];
    const float* proj1_b = (const float*)d_in[6];
    const float* ln2_g   = (const float*)d_in[7];
    const float* ln2_b   = (const float*)d_in[8];
    const float* qkv2_w  = (const float*)d_in[9];
    const float* qkv2_b  = (const float*)d_in[10];
    const float* proj2_w = (const float*)d_in[11];
    const float* proj2_b = (const float*)d_in[12];
    float* out = (float*)d_out;
    u16*   wsp = (u16*)d_ws;

    prep_weights<<<dim3(432), dim3(256), 0, stream>>>(qkv1_w, proj1_w, qkv2_w, proj2_w, wsp);
    swin_branch<0><<<dim3(256), dim3(768), 0, stream>>>(x,   out, ln1_g, ln1_b,
                                                        wsp,        qkv1_b, wsp+110592, proj1_b);
    swin_branch<4><<<dim3(256), dim3(768), 0, stream>>>(out, out, ln2_g, ln2_b,
                                                        wsp+147456, qkv2_b, wsp+258048, proj2_b);
}

// Round 16
// 288.301 us; speedup vs baseline: 1.6957x; 1.6957x over previous
//
#include <hip/hip_runtime.h>

typedef unsigned int   u32;
typedef unsigned short u16;
typedef __bf16 bf16x8 __attribute__((ext_vector_type(8)));
typedef float  f32x4  __attribute__((ext_vector_type(4)));

__device__ __forceinline__ u16 f2bf(float f) {
    u32 u = __builtin_bit_cast(u32, f);
    u += 0x7FFFu + ((u >> 16) & 1u);
    return (u16)(u >> 16);
}
// packed f32x2 -> bf16x2 (RNE), single instruction
__device__ __forceinline__ u32 cvtpk(float a, float b) {
    u32 r;
    asm("v_cvt_pk_bf16_f32 %0, %1, %2" : "=v"(r) : "v"(a), "v"(b));
    return r;
}
__device__ __forceinline__ bf16x8 ldfrag(const u16* p) {
    return __builtin_bit_cast(bf16x8, *reinterpret_cast<const uint4*>(p));
}

// bank-conflict swizzle on the 16B-chunk index (0..63): fold bits[5:3] into [2:0].
__device__ __forceinline__ u32 swz(u32 i) { return i ^ ((i >> 3) & 7u); }

// ---------------------------------------------------------------------------
// Fused Swin branch, R16 = R12 (best: 156us/branch) with phase 4 rebuilt:
//   - proj MFMA operands SWAPPED (attn-out frags serve as B operand -- A/B
//     share the chunk formula, so the LDS reads are unchanged). D-layout
//     becomes channel-on-(4lg+rg) x token-on-lr, so residual read + store
//     are float4 (16B/lane): 8+8 vector ops/thread vs 32+32 scalar.
//   - residual xin loads issued BEFORE the proj GEMM loop (no LDS dep):
//     ~200cy L2 latency hides under ~750cy of MFMA. Intra-phase overlap --
//     no barrier crossed, so the L2-locality invariant (R9/R13/R15 failures)
//     is untouched.
// WG = 768 threads = 12 waves = TWO windows (balanced 3 waves/SIMD; 2-WG
// co-residency impossible at our >128-reg footprint -- R8/R14 evidence).
// Per-window LDS (u16, base=win*24576): [0,12288) yln 24 frag blocks
// (phase 3: wave w's blocks {s*6+w} = K scratch -> P(ks=1) -> O^T);
// [12288,24576) qreg 4 blocks/head (Q -> P(ks=0) -> V^T).
// ---------------------------------------------------------------------------
template<int SHIFT>
__global__ __launch_bounds__(768) void swin_branch(
    const float* __restrict__ xin, float* __restrict__ xout,
    const float* __restrict__ ln_g, const float* __restrict__ ln_b,
    const u16*   __restrict__ wqkv_t,  // [576][192] bf16 (pre-transposed)
    const float* __restrict__ qkv_b,   // [576]
    const u16*   __restrict__ wproj_t, // [192][192] bf16 (pre-transposed)
    const float* __restrict__ proj_b)  // [192]
{
    __shared__ __align__(16) u16 smem[49152];
    __shared__ float red1[2][6][64];
    __shared__ float red2[2][6][64];
    constexpr u32 QOFF = 12288;
    constexpr float QSC = 0.17677669529663689f * 1.4426950408889634f; // 1/sqrt(32)*log2(e)

    const int tid  = threadIdx.x;
    const int win  = (tid >= 384) ? 1 : 0;
    const int lt   = tid - win*384;
    const int wid  = lt >> 6;               // wave == head
    const int lane = lt & 63;
    const int lr   = lane & 15;
    const int lg   = lane >> 4;
    const u32 lsw  = swz((u32)lane);
    const u32 SB   = (u32)win * 24576u;

    const int Wid = blockIdx.x*2 + win;     // b*256 + wy*16 + wx
    const int b   = Wid >> 8;
    const int wy  = (Wid >> 4) & 15;
    const int wx  = Wid & 15;

    // ---- Phase 1: gather window (rolled), LayerNorm -> yln (frag layout) ----
    {
        const int ty = lane >> 3, tx = lane & 7;
        const int shy = (wy*8 + ty + SHIFT) & 127;
        const int shx = (wx*8 + tx + SHIFT) & 127;
        const float* xp = xin + ((size_t)((b*128 + shy)*128 + shx))*192 + wid*32;
        float xv[32];
        float s1 = 0.f, s2 = 0.f;
        #pragma unroll
        for (int j = 0; j < 8; ++j) {
            float4 v = reinterpret_cast<const float4*>(xp)[j];
            xv[j*4+0]=v.x; xv[j*4+1]=v.y; xv[j*4+2]=v.z; xv[j*4+3]=v.w;
            s1 += v.x+v.y+v.z+v.w;
            s2 += v.x*v.x + v.y*v.y + v.z*v.z + v.w*v.w;
        }
        red1[win][wid][lane] = s1; red2[win][wid][lane] = s2;
        __syncthreads();
        float a1 = 0.f, a2 = 0.f;
        #pragma unroll
        for (int w = 0; w < 6; ++w) { a1 += red1[win][w][lane]; a2 += red2[win][w][lane]; }
        const float mu = a1 * (1.f/192.f);
        const float rs = rsqrtf(a2 * (1.f/192.f) - mu*mu + 1e-5f);
        const float* gp = ln_g + wid*32;
        const float* bp = ln_b + wid*32;
        const u32 yblk = SB + (u32)((lg*6 + wid)*512);
        #pragma unroll
        for (int cc8 = 0; cc8 < 4; ++cc8) {
            u32 pk[4];
            #pragma unroll
            for (int q = 0; q < 4; ++q) {
                int j = cc8*8 + q*2;
                float y0 = (xv[j]   - mu)*rs*gp[j]   + bp[j];
                float y1 = (xv[j+1] - mu)*rs*gp[j+1] + bp[j+1];
                pk[q] = cvtpk(y0, y1);
            }
            *reinterpret_cast<uint4*>(&smem[yblk + swz((u32)(lr + 16*cc8))*8]) =
                make_uint4(pk[0],pk[1],pk[2],pk[3]);
        }
    }
    __syncthreads();

    // ---- Phase 2: QKV GEMM ----
    uint2 kpk[4][2];     // K^T packed bf16 (crosses barrier in regs)
    uint2 vpk[4][2];     // V  packed bf16 (crosses barrier in regs)
    {
        // pass 1 (SWAPPED): Q^T,K^T = mfma(W-frag, yln-frag)
        // D: lane holds X^T[d=16t+4lg+rg][token=16mi+lr]
        {
            f32x4 acc[4][4];
            #pragma unroll
            for (int mi=0; mi<4; ++mi)
                #pragma unroll
                for (int t=0; t<4; ++t) acc[mi][t] = f32x4{0.f,0.f,0.f,0.f};
            #pragma unroll
            for (int ks=0; ks<6; ++ks) {
                bf16x8 af[4];
                #pragma unroll
                for (int mi=0; mi<4; ++mi)
                    af[mi] = ldfrag(&smem[SB + (u32)((mi*6+ks)*512) + lsw*8]);
                bf16x8 bw[4];
                #pragma unroll
                for (int t=0; t<4; ++t)
                    bw[t] = ldfrag(&wqkv_t[((t>>1)*192 + wid*32 + (t&1)*16 + lr)*192 + 32*ks + 8*lg]);
                #pragma unroll
                for (int mi=0; mi<4; ++mi)
                    #pragma unroll
                    for (int t=0; t<4; ++t)
                        acc[mi][t] = __builtin_amdgcn_mfma_f32_16x16x32_bf16(bw[t], af[mi], acc[mi][t], 0,0,0);
            }
            // Q: bias + QSC scale -> qreg as B-frag (uint2 writes, wave-private)
            #pragma unroll
            for (int t=0; t<2; ++t) {
                const float4 b4 = *reinterpret_cast<const float4*>(&qkv_b[wid*32 + t*16 + 4*lg]);
                const u32 chunk = (u32)lr + 16u*(u32)(2*t + (lg>>1));
                #pragma unroll
                for (int mi=0; mi<4; ++mi) {
                    float v0 = (acc[mi][t][0] + b4.x) * QSC;
                    float v1 = (acc[mi][t][1] + b4.y) * QSC;
                    float v2 = (acc[mi][t][2] + b4.z) * QSC;
                    float v3 = (acc[mi][t][3] + b4.w) * QSC;
                    *reinterpret_cast<uint2*>(
                        &smem[SB + QOFF + (u32)(wid*2048) + mi*512 + swz(chunk)*8 + 4*(lg&1)]) =
                        make_uint2(cvtpk(v0,v1), cvtpk(v2,v3));
                }
            }
            // K: bias -> kpk regs
            #pragma unroll
            for (int t2=0; t2<2; ++t2) {
                const float4 b4 = *reinterpret_cast<const float4*>(&qkv_b[192 + wid*32 + t2*16 + 4*lg]);
                #pragma unroll
                for (int mi=0; mi<4; ++mi)
                    kpk[mi][t2] = make_uint2(
                        cvtpk(acc[mi][2+t2][0] + b4.x, acc[mi][2+t2][1] + b4.y),
                        cvtpk(acc[mi][2+t2][2] + b4.z, acc[mi][2+t2][3] + b4.w));
            }
        }
        // pass 2 (unswapped): V = mfma(yln, Wv); lane holds V[token=16mi+4lg+rg][d=16tv+lr]
        {
            f32x4 acc[4][2];
            #pragma unroll
            for (int mi=0; mi<4; ++mi)
                #pragma unroll
                for (int t=0; t<2; ++t) acc[mi][t] = f32x4{0.f,0.f,0.f,0.f};
            #pragma unroll
            for (int ks=0; ks<6; ++ks) {
                bf16x8 af[4];
                #pragma unroll
                for (int mi=0; mi<4; ++mi)
                    af[mi] = ldfrag(&smem[SB + (u32)((mi*6+ks)*512) + lsw*8]);
                bf16x8 bw[2];
                #pragma unroll
                for (int t=0; t<2; ++t)
                    bw[t] = ldfrag(&wqkv_t[(384 + wid*32 + t*16 + lr)*192 + 32*ks + 8*lg]);
                #pragma unroll
                for (int mi=0; mi<4; ++mi)
                    #pragma unroll
                    for (int t=0; t<2; ++t)
                        acc[mi][t] = __builtin_amdgcn_mfma_f32_16x16x32_bf16(af[mi], bw[t], acc[mi][t], 0,0,0);
            }
            #pragma unroll
            for (int tv=0; tv<2; ++tv) {
                const float bias = qkv_b[384 + wid*32 + tv*16 + lr];
                #pragma unroll
                for (int mi=0; mi<4; ++mi)
                    vpk[mi][tv] = make_uint2(
                        cvtpk(acc[mi][tv][0] + bias, acc[mi][tv][1] + bias),
                        cvtpk(acc[mi][tv][2] + bias, acc[mi][tv][3] + bias));
            }
        }
    }
    __syncthreads();   // yln reads done -> wave w's blocks {s*6+w} become scratch

    // ---- Phase 3: attention (all-swapped, wave-local) ----
    float rsum[4];       // per q-col tile nq (q is lane-local on lr)
    f32x4 o_[2][4];      // O^T [dv][nq]
    {
        const u32 W  = SB + (u32)(wid*512);
        const u32 QB = SB + QOFF + (u32)(wid*2048);
        #define BLK(s) ((u32)(s)*3072u + W)

        // K scatter (A-frag): block mi, chunk = lr + 16*(2t2+(lg>>1))
        #pragma unroll
        for (int t2=0; t2<2; ++t2) {
            const u32 chunk = (u32)lr + 16u*(u32)(2*t2 + (lg>>1));
            #pragma unroll
            for (int mi=0; mi<4; ++mi)
                *reinterpret_cast<uint2*>(
                    &smem[BLK(mi) + swz(chunk)*8 + 4*(lg&1)]) = kpk[mi][t2];
        }
        bf16x8 ak[4], bq[4];
        #pragma unroll
        for (int mi=0; mi<4; ++mi) ak[mi] = ldfrag(&smem[BLK(mi) + lsw*8]);
        #pragma unroll
        for (int nq=0; nq<4; ++nq) bq[nq] = ldfrag(&smem[QB + nq*512 + lsw*8]);
        __builtin_amdgcn_sched_barrier(0);

        // q-col classes (per nq; col qt = 16nq+lr)
        int qcl[4];
        if constexpr (SHIFT > 0) {
            #pragma unroll
            for (int nq=0; nq<4; ++nq) {
                const int qt = 16*nq + lr;
                const int hu = wy*8 + (qt>>3);
                const int wu = wx*8 + (qt&7);
                qcl[nq] = ((hu >= 124) ? 2 : (hu >= 120 ? 1 : 0))*3
                        + ((wu >= 124) ? 2 : (wu >= 120 ? 1 : 0));
            }
        }

        // S^T = mfma(K,Q); exp2 (q pre-scaled by log2e/sqrt(d)); zero-mask; pack
        uint2 p16[4][4];    // [mi][nq]
        #pragma unroll
        for (int mi=0; mi<4; ++mi) {
            f32x4 sr[4];
            #pragma unroll
            for (int nq=0; nq<4; ++nq)
                sr[nq] = __builtin_amdgcn_mfma_f32_16x16x32_bf16(ak[mi], bq[nq],
                             f32x4{0.f,0.f,0.f,0.f}, 0,0,0);
            #pragma unroll
            for (int rg=0; rg<4; ++rg) {
                int kcl = 0;
                if constexpr (SHIFT > 0) {
                    const int kt = 16*mi + 4*lg + rg;
                    const int hu = wy*8 + (kt>>3);
                    const int wu = wx*8 + (kt&7);
                    kcl = ((hu >= 124) ? 2 : (hu >= 120 ? 1 : 0))*3
                        + ((wu >= 124) ? 2 : (wu >= 120 ? 1 : 0));
                }
                #pragma unroll
                for (int nq=0; nq<4; ++nq) {
                    float e = exp2f(sr[nq][rg]);
                    if constexpr (SHIFT > 0)
                        e = (kcl == qcl[nq]) ? e : 0.f;
                    sr[nq][rg] = e;
                }
            }
            #pragma unroll
            for (int nq=0; nq<4; ++nq)
                p16[mi][nq] = make_uint2(cvtpk(sr[nq][0], sr[nq][1]),
                                         cvtpk(sr[nq][2], sr[nq][3]));
        }

        // P^T scatter (B-frag): block(nq, ks=mi>>1): ks0 -> QB(nq), ks1 -> BLK(nq)
        #pragma unroll
        for (int mi=0; mi<4; ++mi) {
            const u32 chunk = (u32)lr + 16u*(u32)(2*(mi&1) + (lg>>1));
            #pragma unroll
            for (int nq=0; nq<4; ++nq) {
                const u32 base = (mi >> 1) ? BLK(nq) : (QB + nq*512);
                *reinterpret_cast<uint2*>(&smem[base + swz(chunk)*8 + 4*(lg&1)]) = p16[mi][nq];
            }
        }
        bf16x8 bp[4][2];
        #pragma unroll
        for (int nq=0; nq<4; ++nq) {
            bp[nq][0] = ldfrag(&smem[QB + nq*512 + lsw*8]);
            bp[nq][1] = ldfrag(&smem[BLK(nq) + lsw*8]);
        }
        __builtin_amdgcn_sched_barrier(0);

        // row sums per q-col via ones-MFMA on P^T B-frags
        bf16x8 aones;
        {
            const u32 one2 = 0x3F803F80u;
            aones = __builtin_bit_cast(bf16x8, make_uint4(one2, one2, one2, one2));
        }
        #pragma unroll
        for (int nq=0; nq<4; ++nq) {
            f32x4 racc = __builtin_amdgcn_mfma_f32_16x16x32_bf16(aones, bp[nq][0],
                             f32x4{0.f,0.f,0.f,0.f}, 0,0,0);
            racc = __builtin_amdgcn_mfma_f32_16x16x32_bf16(aones, bp[nq][1], racc, 0,0,0);
            rsum[nq] = __builtin_amdgcn_rcpf(racc[0]);
        }

        // V^T scatter (A-frag) into QB blocks (P ks=0 dead after bp reads)
        #pragma unroll
        for (int mi=0; mi<4; ++mi) {
            const u32 chunk = (u32)lr + 16u*(u32)(2*(mi&1) + (lg>>1));
            #pragma unroll
            for (int tv=0; tv<2; ++tv)
                *reinterpret_cast<uint2*>(
                    &smem[QB + (u32)((2*tv + (mi>>1))*512) + swz(chunk)*8 + 4*(lg&1)]) = vpk[mi][tv];
        }
        bf16x8 av[2][2];
        #pragma unroll
        for (int dv=0; dv<2; ++dv)
            #pragma unroll
            for (int ks=0; ks<2; ++ks)
                av[dv][ks] = ldfrag(&smem[QB + (u32)((2*dv + ks)*512) + lsw*8]);
        __builtin_amdgcn_sched_barrier(0);

        // O^T = V^T * P^T
        #pragma unroll
        for (int dv=0; dv<2; ++dv)
            #pragma unroll
            for (int nq=0; nq<4; ++nq) {
                o_[dv][nq] = __builtin_amdgcn_mfma_f32_16x16x32_bf16(av[dv][0], bp[nq][0],
                                 f32x4{0.f,0.f,0.f,0.f}, 0,0,0);
                o_[dv][nq] = __builtin_amdgcn_mfma_f32_16x16x32_bf16(av[dv][1], bp[nq][1],
                                 o_[dv][nq], 0,0,0);
            }
        __builtin_amdgcn_sched_barrier(0);

        // normalized attn_out -> proj A/B-frag blocks BLK(nq) (uint2 writes)
        #pragma unroll
        for (int dv=0; dv<2; ++dv) {
            const u32 chunk = (u32)lr + 16u*(u32)(2*dv + (lg>>1));
            #pragma unroll
            for (int nq=0; nq<4; ++nq) {
                const float r = rsum[nq];
                *reinterpret_cast<uint2*>(&smem[BLK(nq) + swz(chunk)*8 + 4*(lg&1)]) =
                    make_uint2(cvtpk(o_[dv][nq][0]*r, o_[dv][nq][1]*r),
                               cvtpk(o_[dv][nq][2]*r, o_[dv][nq][3]*r));
            }
        }
        #undef BLK
    }
    __syncthreads();

    // ---- Phase 4: SWAPPED proj GEMM + float4 residual/store ----
    // PROJ^T = mfma(Wp-frag, attnout-frag): D has channel c=wid*32+16ni+4lg+rg,
    // token = 16mi+lr -> 4 consecutive channels per lane = float4 I/O.
    {
        // residual loads issued FIRST (no LDS dep; L2-hot) to hide under GEMM
        float4 xr[4][2];
        #pragma unroll
        for (int ni=0; ni<2; ++ni) {
            const int c0 = wid*32 + 16*ni + 4*lg;
            #pragma unroll
            for (int mi=0; mi<4; ++mi) {
                const int token = 16*mi + lr;
                const int shy = (wy*8 + (token>>3) + SHIFT) & 127;
                const int shx = (wx*8 + (token&7) + SHIFT) & 127;
                const size_t idx = ((size_t)((b*128+shy)*128+shx))*192 + c0;
                xr[mi][ni] = *reinterpret_cast<const float4*>(&xin[idx]);
            }
        }

        f32x4 a2[4][2];
        #pragma unroll
        for (int mi=0; mi<4; ++mi)
            #pragma unroll
            for (int ni=0; ni<2; ++ni) a2[mi][ni] = f32x4{0.f,0.f,0.f,0.f};
        #pragma unroll
        for (int ks=0; ks<6; ++ks) {
            bf16x8 af[4], bw[2];
            #pragma unroll
            for (int mi=0; mi<4; ++mi)
                af[mi] = ldfrag(&smem[SB + (u32)((mi*6+ks)*512) + lsw*8]);
            #pragma unroll
            for (int ni=0; ni<2; ++ni)
                bw[ni] = ldfrag(&wproj_t[(wid*32 + 16*ni + lr)*192 + 32*ks + 8*lg]);
            #pragma unroll
            for (int mi=0; mi<4; ++mi)
                #pragma unroll
                for (int ni=0; ni<2; ++ni)
                    a2[mi][ni] = __builtin_amdgcn_mfma_f32_16x16x32_bf16(bw[ni], af[mi], a2[mi][ni], 0,0,0);
        }
        #pragma unroll
        for (int ni=0; ni<2; ++ni) {
            const int c0 = wid*32 + 16*ni + 4*lg;
            const float4 pb4 = *reinterpret_cast<const float4*>(&proj_b[c0]);
            #pragma unroll
            for (int mi=0; mi<4; ++mi) {
                const int token = 16*mi + lr;
                const int shy = (wy*8 + (token>>3) + SHIFT) & 127;
                const int shx = (wx*8 + (token&7) + SHIFT) & 127;
                const size_t idx = ((size_t)((b*128+shy)*128+shx))*192 + c0;
                float4 o;
                o.x = xr[mi][ni].x + a2[mi][ni][0] + pb4.x;
                o.y = xr[mi][ni].y + a2[mi][ni][1] + pb4.y;
                o.z = xr[mi][ni].z + a2[mi][ni][2] + pb4.z;
                o.w = xr[mi][ni].w + a2[mi][ni][3] + pb4.w;
                *reinterpret_cast<float4*>(&xout[idx]) = o;
            }
        }
    }
}

// ws layout (u16): [0) wqkv1_t 110592 | 110592) wproj1_t 36864 | 147456) wqkv2_t 110592 | 258048) wproj2_t 36864
__global__ void prep_weights(const float* __restrict__ qkv1, const float* __restrict__ proj1,
                             const float* __restrict__ qkv2, const float* __restrict__ proj2,
                             u16* __restrict__ ws)
{
    const int i = blockIdx.x*blockDim.x + threadIdx.x;
    if (i < 110592) {
        const int n = i / 192, k = i - n*192;
        ws[i]          = f2bf(qkv1[k*576 + n]);
        ws[147456 + i] = f2bf(qkv2[k*576 + n]);
    }
    if (i < 36864) {
        const int n = i / 192, k = i - n*192;
        ws[110592 + i] = f2bf(proj1[k*192 + n]);
        ws[258048 + i] = f2bf(proj2[k*192 + n]);
    }
}

extern "C" void kernel_launch(void* const* d_in, const int* in_sizes, int n_in,
                              void* d_out, int out_size, void* d_ws, size_t ws_size,
                              hipStream_t stream)
{
    const float* x       = (const float*)d_in[0];
    const float* ln1_g   = (const float*)d_in[1];
    const float* ln1_b   = (const float*)d_in[2];
    const float* qkv1_w  = (const float*)d_in[3];
    const float* qkv1_b  = (const float*)d_in[4];
    const float* proj1_w = (const float*)d_in[5];
    const float* proj1_b = (const float*)d_in[6];
    const float* ln2_g   = (const float*)d_in[7];
    const float* ln2_b   = (const float*)d_in[8];
    const float* qkv2_w  = (const float*)d_in[9];
    const float* qkv2_b  = (const float*)d_in[10];
    const float* proj2_w = (const float*)d_in[11];
    const float* proj2_b = (const float*)d_in[12];
    float* out = (float*)d_out;
    u16*   wsp = (u16*)d_ws;

    prep_weights<<<dim3(432), dim3(256), 0, stream>>>(qkv1_w, proj1_w, qkv2_w, proj2_w, wsp);
    swin_branch<0><<<dim3(1024), dim3(768), 0, stream>>>(x,   out, ln1_g, ln1_b,
                                                         wsp,        qkv1_b, wsp+110592, proj1_b);
    swin_branch<4><<<dim3(1024), dim3(768), 0, stream>>>(out, out, ln2_g, ln2_b,
                                                         wsp+147456, qkv2_b, wsp+258048, proj2_b);
}

// Round 17
// 284.137 us; speedup vs baseline: 1.7205x; 1.0147x over previous
//
#include <hip/hip_runtime.h>

typedef unsigned int   u32;
typedef unsigned short u16;
typedef __bf16 bf16x8 __attribute__((ext_vector_type(8)));
typedef float  f32x4  __attribute__((ext_vector_type(4)));

__device__ __forceinline__ u16 f2bf(float f) {
    u32 u = __builtin_bit_cast(u32, f);
    u += 0x7FFFu + ((u >> 16) & 1u);
    return (u16)(u >> 16);
}
// packed f32x2 -> bf16x2 (RNE), single instruction
__device__ __forceinline__ u32 cvtpk(float a, float b) {
    u32 r;
    asm("v_cvt_pk_bf16_f32 %0, %1, %2" : "=v"(r) : "v"(a), "v"(b));
    return r;
}
__device__ __forceinline__ bf16x8 ldfrag(const u16* p) {
    return __builtin_bit_cast(bf16x8, *reinterpret_cast<const uint4*>(p));
}

// bank-conflict swizzle on the 16B-chunk index (0..63): fold bits[5:3] into [2:0].
__device__ __forceinline__ u32 swz(u32 i) { return i ^ ((i >> 3) & 7u); }

// ---------------------------------------------------------------------------
// Fused Swin branch, R17 = R12 + swapped-proj float4 P4 (from R16) with the
// residual loads back in the EPILOGUE (R16's only other delta was hoisting
// them before the GEMM, which regressed 156->173us/branch; this round is the
// clean A/B isolating the hoist from the vectorization).
// WG = 768 threads = 12 waves = TWO windows (balanced 3 waves/SIMD; 2-WG
// co-residency impossible at our >128-reg footprint -- R8/R14 evidence;
// cross-phase prefetch breaks residual L2 locality -- R9/R13/R15 evidence).
// Per-window LDS (u16, base=win*24576): [0,12288) yln 24 frag blocks
// (phase 3: wave w's blocks {s*6+w} = K scratch -> P(ks=1) -> O^T);
// [12288,24576) qreg 4 blocks/head (Q -> P(ks=0) -> V^T).
// ---------------------------------------------------------------------------
template<int SHIFT>
__global__ __launch_bounds__(768) void swin_branch(
    const float* __restrict__ xin, float* __restrict__ xout,
    const float* __restrict__ ln_g, const float* __restrict__ ln_b,
    const u16*   __restrict__ wqkv_t,  // [576][192] bf16 (pre-transposed)
    const float* __restrict__ qkv_b,   // [576]
    const u16*   __restrict__ wproj_t, // [192][192] bf16 (pre-transposed)
    const float* __restrict__ proj_b)  // [192]
{
    __shared__ __align__(16) u16 smem[49152];
    __shared__ float red1[2][6][64];
    __shared__ float red2[2][6][64];
    constexpr u32 QOFF = 12288;
    constexpr float QSC = 0.17677669529663689f * 1.4426950408889634f; // 1/sqrt(32)*log2(e)

    const int tid  = threadIdx.x;
    const int win  = (tid >= 384) ? 1 : 0;
    const int lt   = tid - win*384;
    const int wid  = lt >> 6;               // wave == head
    const int lane = lt & 63;
    const int lr   = lane & 15;
    const int lg   = lane >> 4;
    const u32 lsw  = swz((u32)lane);
    const u32 SB   = (u32)win * 24576u;

    const int Wid = blockIdx.x*2 + win;     // b*256 + wy*16 + wx
    const int b   = Wid >> 8;
    const int wy  = (Wid >> 4) & 15;
    const int wx  = Wid & 15;

    // ---- Phase 1: gather window (rolled), LayerNorm -> yln (frag layout) ----
    {
        const int ty = lane >> 3, tx = lane & 7;
        const int shy = (wy*8 + ty + SHIFT) & 127;
        const int shx = (wx*8 + tx + SHIFT) & 127;
        const float* xp = xin + ((size_t)((b*128 + shy)*128 + shx))*192 + wid*32;
        float xv[32];
        float s1 = 0.f, s2 = 0.f;
        #pragma unroll
        for (int j = 0; j < 8; ++j) {
            float4 v = reinterpret_cast<const float4*>(xp)[j];
            xv[j*4+0]=v.x; xv[j*4+1]=v.y; xv[j*4+2]=v.z; xv[j*4+3]=v.w;
            s1 += v.x+v.y+v.z+v.w;
            s2 += v.x*v.x + v.y*v.y + v.z*v.z + v.w*v.w;
        }
        red1[win][wid][lane] = s1; red2[win][wid][lane] = s2;
        __syncthreads();
        float a1 = 0.f, a2 = 0.f;
        #pragma unroll
        for (int w = 0; w < 6; ++w) { a1 += red1[win][w][lane]; a2 += red2[win][w][lane]; }
        const float mu = a1 * (1.f/192.f);
        const float rs = rsqrtf(a2 * (1.f/192.f) - mu*mu + 1e-5f);
        const float* gp = ln_g + wid*32;
        const float* bp = ln_b + wid*32;
        const u32 yblk = SB + (u32)((lg*6 + wid)*512);
        #pragma unroll
        for (int cc8 = 0; cc8 < 4; ++cc8) {
            u32 pk[4];
            #pragma unroll
            for (int q = 0; q < 4; ++q) {
                int j = cc8*8 + q*2;
                float y0 = (xv[j]   - mu)*rs*gp[j]   + bp[j];
                float y1 = (xv[j+1] - mu)*rs*gp[j+1] + bp[j+1];
                pk[q] = cvtpk(y0, y1);
            }
            *reinterpret_cast<uint4*>(&smem[yblk + swz((u32)(lr + 16*cc8))*8]) =
                make_uint4(pk[0],pk[1],pk[2],pk[3]);
        }
    }
    __syncthreads();

    // ---- Phase 2: QKV GEMM ----
    uint2 kpk[4][2];     // K^T packed bf16 (crosses barrier in regs)
    uint2 vpk[4][2];     // V  packed bf16 (crosses barrier in regs)
    {
        // pass 1 (SWAPPED): Q^T,K^T = mfma(W-frag, yln-frag)
        // D: lane holds X^T[d=16t+4lg+rg][token=16mi+lr]
        {
            f32x4 acc[4][4];
            #pragma unroll
            for (int mi=0; mi<4; ++mi)
                #pragma unroll
                for (int t=0; t<4; ++t) acc[mi][t] = f32x4{0.f,0.f,0.f,0.f};
            #pragma unroll
            for (int ks=0; ks<6; ++ks) {
                bf16x8 af[4];
                #pragma unroll
                for (int mi=0; mi<4; ++mi)
                    af[mi] = ldfrag(&smem[SB + (u32)((mi*6+ks)*512) + lsw*8]);
                bf16x8 bw[4];
                #pragma unroll
                for (int t=0; t<4; ++t)
                    bw[t] = ldfrag(&wqkv_t[((t>>1)*192 + wid*32 + (t&1)*16 + lr)*192 + 32*ks + 8*lg]);
                #pragma unroll
                for (int mi=0; mi<4; ++mi)
                    #pragma unroll
                    for (int t=0; t<4; ++t)
                        acc[mi][t] = __builtin_amdgcn_mfma_f32_16x16x32_bf16(bw[t], af[mi], acc[mi][t], 0,0,0);
            }
            // Q: bias + QSC scale -> qreg as B-frag (uint2 writes, wave-private)
            #pragma unroll
            for (int t=0; t<2; ++t) {
                const float4 b4 = *reinterpret_cast<const float4*>(&qkv_b[wid*32 + t*16 + 4*lg]);
                const u32 chunk = (u32)lr + 16u*(u32)(2*t + (lg>>1));
                #pragma unroll
                for (int mi=0; mi<4; ++mi) {
                    float v0 = (acc[mi][t][0] + b4.x) * QSC;
                    float v1 = (acc[mi][t][1] + b4.y) * QSC;
                    float v2 = (acc[mi][t][2] + b4.z) * QSC;
                    float v3 = (acc[mi][t][3] + b4.w) * QSC;
                    *reinterpret_cast<uint2*>(
                        &smem[SB + QOFF + (u32)(wid*2048) + mi*512 + swz(chunk)*8 + 4*(lg&1)]) =
                        make_uint2(cvtpk(v0,v1), cvtpk(v2,v3));
                }
            }
            // K: bias -> kpk regs
            #pragma unroll
            for (int t2=0; t2<2; ++t2) {
                const float4 b4 = *reinterpret_cast<const float4*>(&qkv_b[192 + wid*32 + t2*16 + 4*lg]);
                #pragma unroll
                for (int mi=0; mi<4; ++mi)
                    kpk[mi][t2] = make_uint2(
                        cvtpk(acc[mi][2+t2][0] + b4.x, acc[mi][2+t2][1] + b4.y),
                        cvtpk(acc[mi][2+t2][2] + b4.z, acc[mi][2+t2][3] + b4.w));
            }
        }
        // pass 2 (unswapped): V = mfma(yln, Wv); lane holds V[token=16mi+4lg+rg][d=16tv+lr]
        {
            f32x4 acc[4][2];
            #pragma unroll
            for (int mi=0; mi<4; ++mi)
                #pragma unroll
                for (int t=0; t<2; ++t) acc[mi][t] = f32x4{0.f,0.f,0.f,0.f};
            #pragma unroll
            for (int ks=0; ks<6; ++ks) {
                bf16x8 af[4];
                #pragma unroll
                for (int mi=0; mi<4; ++mi)
                    af[mi] = ldfrag(&smem[SB + (u32)((mi*6+ks)*512) + lsw*8]);
                bf16x8 bw[2];
                #pragma unroll
                for (int t=0; t<2; ++t)
                    bw[t] = ldfrag(&wqkv_t[(384 + wid*32 + t*16 + lr)*192 + 32*ks + 8*lg]);
                #pragma unroll
                for (int mi=0; mi<4; ++mi)
                    #pragma unroll
                    for (int t=0; t<2; ++t)
                        acc[mi][t] = __builtin_amdgcn_mfma_f32_16x16x32_bf16(af[mi], bw[t], acc[mi][t], 0,0,0);
            }
            #pragma unroll
            for (int tv=0; tv<2; ++tv) {
                const float bias = qkv_b[384 + wid*32 + tv*16 + lr];
                #pragma unroll
                for (int mi=0; mi<4; ++mi)
                    vpk[mi][tv] = make_uint2(
                        cvtpk(acc[mi][tv][0] + bias, acc[mi][tv][1] + bias),
                        cvtpk(acc[mi][tv][2] + bias, acc[mi][tv][3] + bias));
            }
        }
    }
    __syncthreads();   // yln reads done -> wave w's blocks {s*6+w} become scratch

    // ---- Phase 3: attention (all-swapped, wave-local) ----
    float rsum[4];       // per q-col tile nq (q is lane-local on lr)
    f32x4 o_[2][4];      // O^T [dv][nq]
    {
        const u32 W  = SB + (u32)(wid*512);
        const u32 QB = SB + QOFF + (u32)(wid*2048);
        #define BLK(s) ((u32)(s)*3072u + W)

        // K scatter (A-frag): block mi, chunk = lr + 16*(2t2+(lg>>1))
        #pragma unroll
        for (int t2=0; t2<2; ++t2) {
            const u32 chunk = (u32)lr + 16u*(u32)(2*t2 + (lg>>1));
            #pragma unroll
            for (int mi=0; mi<4; ++mi)
                *reinterpret_cast<uint2*>(
                    &smem[BLK(mi) + swz(chunk)*8 + 4*(lg&1)]) = kpk[mi][t2];
        }
        bf16x8 ak[4], bq[4];
        #pragma unroll
        for (int mi=0; mi<4; ++mi) ak[mi] = ldfrag(&smem[BLK(mi) + lsw*8]);
        #pragma unroll
        for (int nq=0; nq<4; ++nq) bq[nq] = ldfrag(&smem[QB + nq*512 + lsw*8]);
        __builtin_amdgcn_sched_barrier(0);

        // q-col classes (per nq; col qt = 16nq+lr)
        int qcl[4];
        if constexpr (SHIFT > 0) {
            #pragma unroll
            for (int nq=0; nq<4; ++nq) {
                const int qt = 16*nq + lr;
                const int hu = wy*8 + (qt>>3);
                const int wu = wx*8 + (qt&7);
                qcl[nq] = ((hu >= 124) ? 2 : (hu >= 120 ? 1 : 0))*3
                        + ((wu >= 124) ? 2 : (wu >= 120 ? 1 : 0));
            }
        }

        // S^T = mfma(K,Q); exp2 (q pre-scaled by log2e/sqrt(d)); zero-mask; pack
        uint2 p16[4][4];    // [mi][nq]
        #pragma unroll
        for (int mi=0; mi<4; ++mi) {
            f32x4 sr[4];
            #pragma unroll
            for (int nq=0; nq<4; ++nq)
                sr[nq] = __builtin_amdgcn_mfma_f32_16x16x32_bf16(ak[mi], bq[nq],
                             f32x4{0.f,0.f,0.f,0.f}, 0,0,0);
            #pragma unroll
            for (int rg=0; rg<4; ++rg) {
                int kcl = 0;
                if constexpr (SHIFT > 0) {
                    const int kt = 16*mi + 4*lg + rg;
                    const int hu = wy*8 + (kt>>3);
                    const int wu = wx*8 + (kt&7);
                    kcl = ((hu >= 124) ? 2 : (hu >= 120 ? 1 : 0))*3
                        + ((wu >= 124) ? 2 : (wu >= 120 ? 1 : 0));
                }
                #pragma unroll
                for (int nq=0; nq<4; ++nq) {
                    float e = exp2f(sr[nq][rg]);
                    if constexpr (SHIFT > 0)
                        e = (kcl == qcl[nq]) ? e : 0.f;
                    sr[nq][rg] = e;
                }
            }
            #pragma unroll
            for (int nq=0; nq<4; ++nq)
                p16[mi][nq] = make_uint2(cvtpk(sr[nq][0], sr[nq][1]),
                                         cvtpk(sr[nq][2], sr[nq][3]));
        }

        // P^T scatter (B-frag): block(nq, ks=mi>>1): ks0 -> QB(nq), ks1 -> BLK(nq)
        #pragma unroll
        for (int mi=0; mi<4; ++mi) {
            const u32 chunk = (u32)lr + 16u*(u32)(2*(mi&1) + (lg>>1));
            #pragma unroll
            for (int nq=0; nq<4; ++nq) {
                const u32 base = (mi >> 1) ? BLK(nq) : (QB + nq*512);
                *reinterpret_cast<uint2*>(&smem[base + swz(chunk)*8 + 4*(lg&1)]) = p16[mi][nq];
            }
        }
        bf16x8 bp[4][2];
        #pragma unroll
        for (int nq=0; nq<4; ++nq) {
            bp[nq][0] = ldfrag(&smem[QB + nq*512 + lsw*8]);
            bp[nq][1] = ldfrag(&smem[BLK(nq) + lsw*8]);
        }
        __builtin_amdgcn_sched_barrier(0);

        // row sums per q-col via ones-MFMA on P^T B-frags
        bf16x8 aones;
        {
            const u32 one2 = 0x3F803F80u;
            aones = __builtin_bit_cast(bf16x8, make_uint4(one2, one2, one2, one2));
        }
        #pragma unroll
        for (int nq=0; nq<4; ++nq) {
            f32x4 racc = __builtin_amdgcn_mfma_f32_16x16x32_bf16(aones, bp[nq][0],
                             f32x4{0.f,0.f,0.f,0.f}, 0,0,0);
            racc = __builtin_amdgcn_mfma_f32_16x16x32_bf16(aones, bp[nq][1], racc, 0,0,0);
            rsum[nq] = __builtin_amdgcn_rcpf(racc[0]);
        }

        // V^T scatter (A-frag) into QB blocks (P ks=0 dead after bp reads)
        #pragma unroll
        for (int mi=0; mi<4; ++mi) {
            const u32 chunk = (u32)lr + 16u*(u32)(2*(mi&1) + (lg>>1));
            #pragma unroll
            for (int tv=0; tv<2; ++tv)
                *reinterpret_cast<uint2*>(
                    &smem[QB + (u32)((2*tv + (mi>>1))*512) + swz(chunk)*8 + 4*(lg&1)]) = vpk[mi][tv];
        }
        bf16x8 av[2][2];
        #pragma unroll
        for (int dv=0; dv<2; ++dv)
            #pragma unroll
            for (int ks=0; ks<2; ++ks)
                av[dv][ks] = ldfrag(&smem[QB + (u32)((2*dv + ks)*512) + lsw*8]);
        __builtin_amdgcn_sched_barrier(0);

        // O^T = V^T * P^T
        #pragma unroll
        for (int dv=0; dv<2; ++dv)
            #pragma unroll
            for (int nq=0; nq<4; ++nq) {
                o_[dv][nq] = __builtin_amdgcn_mfma_f32_16x16x32_bf16(av[dv][0], bp[nq][0],
                                 f32x4{0.f,0.f,0.f,0.f}, 0,0,0);
                o_[dv][nq] = __builtin_amdgcn_mfma_f32_16x16x32_bf16(av[dv][1], bp[nq][1],
                                 o_[dv][nq], 0,0,0);
            }
        __builtin_amdgcn_sched_barrier(0);

        // normalized attn_out -> proj frag blocks BLK(nq) (uint2 writes)
        #pragma unroll
        for (int dv=0; dv<2; ++dv) {
            const u32 chunk = (u32)lr + 16u*(u32)(2*dv + (lg>>1));
            #pragma unroll
            for (int nq=0; nq<4; ++nq) {
                const float r = rsum[nq];
                *reinterpret_cast<uint2*>(&smem[BLK(nq) + swz(chunk)*8 + 4*(lg&1)]) =
                    make_uint2(cvtpk(o_[dv][nq][0]*r, o_[dv][nq][1]*r),
                               cvtpk(o_[dv][nq][2]*r, o_[dv][nq][3]*r));
            }
        }
        #undef BLK
    }
    __syncthreads();

    // ---- Phase 4: SWAPPED proj GEMM; residual loads in EPILOGUE (R12 slot) ----
    // PROJ^T = mfma(Wp-frag, attnout-frag): D has channel c=wid*32+16ni+4lg+rg,
    // token = 16mi+lr -> 4 consecutive channels per lane = float4 I/O.
    {
        f32x4 a2[4][2];
        #pragma unroll
        for (int mi=0; mi<4; ++mi)
            #pragma unroll
            for (int ni=0; ni<2; ++ni) a2[mi][ni] = f32x4{0.f,0.f,0.f,0.f};
        #pragma unroll
        for (int ks=0; ks<6; ++ks) {
            bf16x8 af[4], bw[2];
            #pragma unroll
            for (int mi=0; mi<4; ++mi)
                af[mi] = ldfrag(&smem[SB + (u32)((mi*6+ks)*512) + lsw*8]);
            #pragma unroll
            for (int ni=0; ni<2; ++ni)
                bw[ni] = ldfrag(&wproj_t[(wid*32 + 16*ni + lr)*192 + 32*ks + 8*lg]);
            #pragma unroll
            for (int mi=0; mi<4; ++mi)
                #pragma unroll
                for (int ni=0; ni<2; ++ni)
                    a2[mi][ni] = __builtin_amdgcn_mfma_f32_16x16x32_bf16(bw[ni], af[mi], a2[mi][ni], 0,0,0);
        }
        #pragma unroll
        for (int ni=0; ni<2; ++ni) {
            const int c0 = wid*32 + 16*ni + 4*lg;
            const float4 pb4 = *reinterpret_cast<const float4*>(&proj_b[c0]);
            #pragma unroll
            for (int mi=0; mi<4; ++mi) {
                const int token = 16*mi + lr;
                const int shy = (wy*8 + (token>>3) + SHIFT) & 127;
                const int shx = (wx*8 + (token&7) + SHIFT) & 127;
                const size_t idx = ((size_t)((b*128+shy)*128+shx))*192 + c0;
                const float4 xr = *reinterpret_cast<const float4*>(&xin[idx]);
                float4 o;
                o.x = xr.x + a2[mi][ni][0] + pb4.x;
                o.y = xr.y + a2[mi][ni][1] + pb4.y;
                o.z = xr.z + a2[mi][ni][2] + pb4.z;
                o.w = xr.w + a2[mi][ni][3] + pb4.w;
                *reinterpret_cast<float4*>(&xout[idx]) = o;
            }
        }
    }
}

// ws layout (u16): [0) wqkv1_t 110592 | 110592) wproj1_t 36864 | 147456) wqkv2_t 110592 | 258048) wproj2_t 36864
__global__ void prep_weights(const float* __restrict__ qkv1, const float* __restrict__ proj1,
                             const float* __restrict__ qkv2, const float* __restrict__ proj2,
                             u16* __restrict__ ws)
{
    const int i = blockIdx.x*blockDim.x + threadIdx.x;
    if (i < 110592) {
        const int n = i / 192, k = i - n*192;
        ws[i]          = f2bf(qkv1[k*576 + n]);
        ws[147456 + i] = f2bf(qkv2[k*576 + n]);
    }
    if (i < 36864) {
        const int n = i / 192, k = i - n*192;
        ws[110592 + i] = f2bf(proj1[k*192 + n]);
        ws[258048 + i] = f2bf(proj2[k*192 + n]);
    }
}

extern "C" void kernel_launch(void* const* d_in, const int* in_sizes, int n_in,
                              void* d_out, int out_size, void* d_ws, size_t ws_size,
                              hipStream_t stream)
{
    const float* x       = (const float*)d_in[0];
    const float* ln1_g   = (const float*)d_in[1];
    const float* ln1_b   = (const float*)d_in[2];
    const float* qkv1_w  = (const float*)d_in[3];
    const float* qkv1_b  = (const float*)d_in[4];
    const float* proj1_w = (const float*)d_in[5];
    const float* proj1_b = (const float*)d_in[6];
    const float* ln2_g   = (const float*)d_in[7];
    const float* ln2_b   = (const float*)d_in[8];
    const float* qkv2_w  = (const float*)d_in[9];
    const float* qkv2_b  = (const float*)d_in[10];
    const float* proj2_w = (const float*)d_in[11];
    const float* proj2_b = (const float*)d_in[12];
    float* out = (float*)d_out;
    u16*   wsp = (u16*)d_ws;

    prep_weights<<<dim3(432), dim3(256), 0, stream>>>(qkv1_w, proj1_w, qkv2_w, proj2_w, wsp);
    swin_branch<0><<<dim3(1024), dim3(768), 0, stream>>>(x,   out, ln1_g, ln1_b,
                                                         wsp,        qkv1_b, wsp+110592, proj1_b);
    swin_branch<4><<<dim3(1024), dim3(768), 0, stream>>>(out, out, ln2_g, ln2_b,
                                                         wsp+147456, qkv2_b, wsp+258048, proj2_b);
}

// Round 18
// 263.051 us; speedup vs baseline: 1.8584x; 1.0802x over previous
//
#include <hip/hip_runtime.h>

typedef unsigned int   u32;
typedef unsigned short u16;
typedef __bf16 bf16x8 __attribute__((ext_vector_type(8)));
typedef float  f32x4  __attribute__((ext_vector_type(4)));

__device__ __forceinline__ u16 f2bf(float f) {
    u32 u = __builtin_bit_cast(u32, f);
    u += 0x7FFFu + ((u >> 16) & 1u);
    return (u16)(u >> 16);
}
// packed f32x2 -> bf16x2 (RNE), single instruction
__device__ __forceinline__ u32 cvtpk(float a, float b) {
    u32 r;
    asm("v_cvt_pk_bf16_f32 %0, %1, %2" : "=v"(r) : "v"(a), "v"(b));
    return r;
}
__device__ __forceinline__ bf16x8 ldfrag(const u16* p) {
    return __builtin_bit_cast(bf16x8, *reinterpret_cast<const uint4*>(p));
}

// bank-conflict swizzle on the 16B-chunk index (0..63): fold bits[5:3] into [2:0].
__device__ __forceinline__ u32 swz(u32 i) { return i ^ ((i >> 3) & 7u); }

// ---------------------------------------------------------------------------
// Fused Swin branch, R18 = R12 restored EXACTLY (best: 156us/branch; R16/R17's
// swapped-P4 float4 epilogue measured SLOWER -- R12's scalar epilogue is
// already 64B-coalesced per lg-group) + T5 s_setprio(1) around the MFMA
// clusters in P2/P3 (waves drift within phases -> priority can shorten the
// critical path; zero-risk hint).
// Established walls (measured): >128-reg footprint => 2nd WG never fits
// (R8/R14 spills); cross-phase x-prefetch breaks residual L2 locality
// (R9/R13/R15 FETCH 2.5-3x). WG = 768 threads = 12 waves = TWO windows.
// Per-window LDS (u16, base=win*24576): [0,12288) yln 24 frag blocks
// (phase 3: wave w's blocks {s*6+w} = K scratch -> P(ks=1) -> O^T);
// [12288,24576) qreg 4 blocks/head (Q -> P(ks=0) -> V^T).
// ---------------------------------------------------------------------------
template<int SHIFT>
__global__ __launch_bounds__(768) void swin_branch(
    const float* __restrict__ xin, float* __restrict__ xout,
    const float* __restrict__ ln_g, const float* __restrict__ ln_b,
    const u16*   __restrict__ wqkv_t,  // [576][192] bf16 (pre-transposed)
    const float* __restrict__ qkv_b,   // [576]
    const u16*   __restrict__ wproj_t, // [192][192] bf16 (pre-transposed)
    const float* __restrict__ proj_b)  // [192]
{
    __shared__ __align__(16) u16 smem[49152];
    __shared__ float red1[2][6][64];
    __shared__ float red2[2][6][64];
    constexpr u32 QOFF = 12288;
    constexpr float QSC = 0.17677669529663689f * 1.4426950408889634f; // 1/sqrt(32)*log2(e)

    const int tid  = threadIdx.x;
    const int win  = (tid >= 384) ? 1 : 0;
    const int lt   = tid - win*384;
    const int wid  = lt >> 6;               // wave == head
    const int lane = lt & 63;
    const int lr   = lane & 15;
    const int lg   = lane >> 4;
    const u32 lsw  = swz((u32)lane);
    const u32 SB   = (u32)win * 24576u;

    const int Wid = blockIdx.x*2 + win;     // b*256 + wy*16 + wx
    const int b   = Wid >> 8;
    const int wy  = (Wid >> 4) & 15;
    const int wx  = Wid & 15;

    // ---- Phase 1: gather window (rolled), LayerNorm -> yln (frag layout) ----
    {
        const int ty = lane >> 3, tx = lane & 7;
        const int shy = (wy*8 + ty + SHIFT) & 127;
        const int shx = (wx*8 + tx + SHIFT) & 127;
        const float* xp = xin + ((size_t)((b*128 + shy)*128 + shx))*192 + wid*32;
        float xv[32];
        float s1 = 0.f, s2 = 0.f;
        #pragma unroll
        for (int j = 0; j < 8; ++j) {
            float4 v = reinterpret_cast<const float4*>(xp)[j];
            xv[j*4+0]=v.x; xv[j*4+1]=v.y; xv[j*4+2]=v.z; xv[j*4+3]=v.w;
            s1 += v.x+v.y+v.z+v.w;
            s2 += v.x*v.x + v.y*v.y + v.z*v.z + v.w*v.w;
        }
        red1[win][wid][lane] = s1; red2[win][wid][lane] = s2;
        __syncthreads();
        float a1 = 0.f, a2 = 0.f;
        #pragma unroll
        for (int w = 0; w < 6; ++w) { a1 += red1[win][w][lane]; a2 += red2[win][w][lane]; }
        const float mu = a1 * (1.f/192.f);
        const float rs = rsqrtf(a2 * (1.f/192.f) - mu*mu + 1e-5f);
        const float* gp = ln_g + wid*32;
        const float* bp = ln_b + wid*32;
        const u32 yblk = SB + (u32)((lg*6 + wid)*512);
        #pragma unroll
        for (int cc8 = 0; cc8 < 4; ++cc8) {
            u32 pk[4];
            #pragma unroll
            for (int q = 0; q < 4; ++q) {
                int j = cc8*8 + q*2;
                float y0 = (xv[j]   - mu)*rs*gp[j]   + bp[j];
                float y1 = (xv[j+1] - mu)*rs*gp[j+1] + bp[j+1];
                pk[q] = cvtpk(y0, y1);
            }
            *reinterpret_cast<uint4*>(&smem[yblk + swz((u32)(lr + 16*cc8))*8]) =
                make_uint4(pk[0],pk[1],pk[2],pk[3]);
        }
    }
    __syncthreads();

    // ---- Phase 2: QKV GEMM ----
    uint2 kpk[4][2];     // K^T packed bf16 (crosses barrier in regs)
    uint2 vpk[4][2];     // V  packed bf16 (crosses barrier in regs)
    {
        // pass 1 (SWAPPED): Q^T,K^T = mfma(W-frag, yln-frag)
        // D: lane holds X^T[d=16t+4lg+rg][token=16mi+lr]
        {
            f32x4 acc[4][4];
            #pragma unroll
            for (int mi=0; mi<4; ++mi)
                #pragma unroll
                for (int t=0; t<4; ++t) acc[mi][t] = f32x4{0.f,0.f,0.f,0.f};
            #pragma unroll
            for (int ks=0; ks<6; ++ks) {
                bf16x8 af[4];
                #pragma unroll
                for (int mi=0; mi<4; ++mi)
                    af[mi] = ldfrag(&smem[SB + (u32)((mi*6+ks)*512) + lsw*8]);
                bf16x8 bw[4];
                #pragma unroll
                for (int t=0; t<4; ++t)
                    bw[t] = ldfrag(&wqkv_t[((t>>1)*192 + wid*32 + (t&1)*16 + lr)*192 + 32*ks + 8*lg]);
                __builtin_amdgcn_s_setprio(1);
                #pragma unroll
                for (int mi=0; mi<4; ++mi)
                    #pragma unroll
                    for (int t=0; t<4; ++t)
                        acc[mi][t] = __builtin_amdgcn_mfma_f32_16x16x32_bf16(bw[t], af[mi], acc[mi][t], 0,0,0);
                __builtin_amdgcn_s_setprio(0);
            }
            // Q: bias + QSC scale -> qreg as B-frag (uint2 writes, wave-private)
            #pragma unroll
            for (int t=0; t<2; ++t) {
                const float4 b4 = *reinterpret_cast<const float4*>(&qkv_b[wid*32 + t*16 + 4*lg]);
                const u32 chunk = (u32)lr + 16u*(u32)(2*t + (lg>>1));
                #pragma unroll
                for (int mi=0; mi<4; ++mi) {
                    float v0 = (acc[mi][t][0] + b4.x) * QSC;
                    float v1 = (acc[mi][t][1] + b4.y) * QSC;
                    float v2 = (acc[mi][t][2] + b4.z) * QSC;
                    float v3 = (acc[mi][t][3] + b4.w) * QSC;
                    *reinterpret_cast<uint2*>(
                        &smem[SB + QOFF + (u32)(wid*2048) + mi*512 + swz(chunk)*8 + 4*(lg&1)]) =
                        make_uint2(cvtpk(v0,v1), cvtpk(v2,v3));
                }
            }
            // K: bias -> kpk regs
            #pragma unroll
            for (int t2=0; t2<2; ++t2) {
                const float4 b4 = *reinterpret_cast<const float4*>(&qkv_b[192 + wid*32 + t2*16 + 4*lg]);
                #pragma unroll
                for (int mi=0; mi<4; ++mi)
                    kpk[mi][t2] = make_uint2(
                        cvtpk(acc[mi][2+t2][0] + b4.x, acc[mi][2+t2][1] + b4.y),
                        cvtpk(acc[mi][2+t2][2] + b4.z, acc[mi][2+t2][3] + b4.w));
            }
        }
        // pass 2 (unswapped): V = mfma(yln, Wv); lane holds V[token=16mi+4lg+rg][d=16tv+lr]
        {
            f32x4 acc[4][2];
            #pragma unroll
            for (int mi=0; mi<4; ++mi)
                #pragma unroll
                for (int t=0; t<2; ++t) acc[mi][t] = f32x4{0.f,0.f,0.f,0.f};
            #pragma unroll
            for (int ks=0; ks<6; ++ks) {
                bf16x8 af[4];
                #pragma unroll
                for (int mi=0; mi<4; ++mi)
                    af[mi] = ldfrag(&smem[SB + (u32)((mi*6+ks)*512) + lsw*8]);
                bf16x8 bw[2];
                #pragma unroll
                for (int t=0; t<2; ++t)
                    bw[t] = ldfrag(&wqkv_t[(384 + wid*32 + t*16 + lr)*192 + 32*ks + 8*lg]);
                __builtin_amdgcn_s_setprio(1);
                #pragma unroll
                for (int mi=0; mi<4; ++mi)
                    #pragma unroll
                    for (int t=0; t<2; ++t)
                        acc[mi][t] = __builtin_amdgcn_mfma_f32_16x16x32_bf16(af[mi], bw[t], acc[mi][t], 0,0,0);
                __builtin_amdgcn_s_setprio(0);
            }
            #pragma unroll
            for (int tv=0; tv<2; ++tv) {
                const float bias = qkv_b[384 + wid*32 + tv*16 + lr];
                #pragma unroll
                for (int mi=0; mi<4; ++mi)
                    vpk[mi][tv] = make_uint2(
                        cvtpk(acc[mi][tv][0] + bias, acc[mi][tv][1] + bias),
                        cvtpk(acc[mi][tv][2] + bias, acc[mi][tv][3] + bias));
            }
        }
    }
    __syncthreads();   // yln reads done -> wave w's blocks {s*6+w} become scratch

    // ---- Phase 3: attention (all-swapped, wave-local) ----
    float rsum[4];       // per q-col tile nq (q is lane-local on lr)
    f32x4 o_[2][4];      // O^T [dv][nq]
    {
        const u32 W  = SB + (u32)(wid*512);
        const u32 QB = SB + QOFF + (u32)(wid*2048);
        #define BLK(s) ((u32)(s)*3072u + W)

        // K scatter (A-frag): block mi, chunk = lr + 16*(2t2+(lg>>1))
        #pragma unroll
        for (int t2=0; t2<2; ++t2) {
            const u32 chunk = (u32)lr + 16u*(u32)(2*t2 + (lg>>1));
            #pragma unroll
            for (int mi=0; mi<4; ++mi)
                *reinterpret_cast<uint2*>(
                    &smem[BLK(mi) + swz(chunk)*8 + 4*(lg&1)]) = kpk[mi][t2];
        }
        bf16x8 ak[4], bq[4];
        #pragma unroll
        for (int mi=0; mi<4; ++mi) ak[mi] = ldfrag(&smem[BLK(mi) + lsw*8]);
        #pragma unroll
        for (int nq=0; nq<4; ++nq) bq[nq] = ldfrag(&smem[QB + nq*512 + lsw*8]);
        __builtin_amdgcn_sched_barrier(0);

        // q-col classes (per nq; col qt = 16nq+lr)
        int qcl[4];
        if constexpr (SHIFT > 0) {
            #pragma unroll
            for (int nq=0; nq<4; ++nq) {
                const int qt = 16*nq + lr;
                const int hu = wy*8 + (qt>>3);
                const int wu = wx*8 + (qt&7);
                qcl[nq] = ((hu >= 124) ? 2 : (hu >= 120 ? 1 : 0))*3
                        + ((wu >= 124) ? 2 : (wu >= 120 ? 1 : 0));
            }
        }

        // S^T = mfma(K,Q); exp2 (q pre-scaled by log2e/sqrt(d)); zero-mask; pack
        uint2 p16[4][4];    // [mi][nq]
        #pragma unroll
        for (int mi=0; mi<4; ++mi) {
            f32x4 sr[4];
            __builtin_amdgcn_s_setprio(1);
            #pragma unroll
            for (int nq=0; nq<4; ++nq)
                sr[nq] = __builtin_amdgcn_mfma_f32_16x16x32_bf16(ak[mi], bq[nq],
                             f32x4{0.f,0.f,0.f,0.f}, 0,0,0);
            __builtin_amdgcn_s_setprio(0);
            #pragma unroll
            for (int rg=0; rg<4; ++rg) {
                int kcl = 0;
                if constexpr (SHIFT > 0) {
                    const int kt = 16*mi + 4*lg + rg;
                    const int hu = wy*8 + (kt>>3);
                    const int wu = wx*8 + (kt&7);
                    kcl = ((hu >= 124) ? 2 : (hu >= 120 ? 1 : 0))*3
                        + ((wu >= 124) ? 2 : (wu >= 120 ? 1 : 0));
                }
                #pragma unroll
                for (int nq=0; nq<4; ++nq) {
                    float e = exp2f(sr[nq][rg]);
                    if constexpr (SHIFT > 0)
                        e = (kcl == qcl[nq]) ? e : 0.f;
                    sr[nq][rg] = e;
                }
            }
            #pragma unroll
            for (int nq=0; nq<4; ++nq)
                p16[mi][nq] = make_uint2(cvtpk(sr[nq][0], sr[nq][1]),
                                         cvtpk(sr[nq][2], sr[nq][3]));
        }

        // P^T scatter (B-frag): block(nq, ks=mi>>1): ks0 -> QB(nq), ks1 -> BLK(nq)
        #pragma unroll
        for (int mi=0; mi<4; ++mi) {
            const u32 chunk = (u32)lr + 16u*(u32)(2*(mi&1) + (lg>>1));
            #pragma unroll
            for (int nq=0; nq<4; ++nq) {
                const u32 base = (mi >> 1) ? BLK(nq) : (QB + nq*512);
                *reinterpret_cast<uint2*>(&smem[base + swz(chunk)*8 + 4*(lg&1)]) = p16[mi][nq];
            }
        }
        bf16x8 bp[4][2];
        #pragma unroll
        for (int nq=0; nq<4; ++nq) {
            bp[nq][0] = ldfrag(&smem[QB + nq*512 + lsw*8]);
            bp[nq][1] = ldfrag(&smem[BLK(nq) + lsw*8]);
        }
        __builtin_amdgcn_sched_barrier(0);

        // row sums per q-col via ones-MFMA on P^T B-frags
        bf16x8 aones;
        {
            const u32 one2 = 0x3F803F80u;
            aones = __builtin_bit_cast(bf16x8, make_uint4(one2, one2, one2, one2));
        }
        #pragma unroll
        for (int nq=0; nq<4; ++nq) {
            f32x4 racc = __builtin_amdgcn_mfma_f32_16x16x32_bf16(aones, bp[nq][0],
                             f32x4{0.f,0.f,0.f,0.f}, 0,0,0);
            racc = __builtin_amdgcn_mfma_f32_16x16x32_bf16(aones, bp[nq][1], racc, 0,0,0);
            rsum[nq] = __builtin_amdgcn_rcpf(racc[0]);
        }

        // V^T scatter (A-frag) into QB blocks (P ks=0 dead after bp reads)
        #pragma unroll
        for (int mi=0; mi<4; ++mi) {
            const u32 chunk = (u32)lr + 16u*(u32)(2*(mi&1) + (lg>>1));
            #pragma unroll
            for (int tv=0; tv<2; ++tv)
                *reinterpret_cast<uint2*>(
                    &smem[QB + (u32)((2*tv + (mi>>1))*512) + swz(chunk)*8 + 4*(lg&1)]) = vpk[mi][tv];
        }
        bf16x8 av[2][2];
        #pragma unroll
        for (int dv=0; dv<2; ++dv)
            #pragma unroll
            for (int ks=0; ks<2; ++ks)
                av[dv][ks] = ldfrag(&smem[QB + (u32)((2*dv + ks)*512) + lsw*8]);
        __builtin_amdgcn_sched_barrier(0);

        // O^T = V^T * P^T
        __builtin_amdgcn_s_setprio(1);
        #pragma unroll
        for (int dv=0; dv<2; ++dv)
            #pragma unroll
            for (int nq=0; nq<4; ++nq) {
                o_[dv][nq] = __builtin_amdgcn_mfma_f32_16x16x32_bf16(av[dv][0], bp[nq][0],
                                 f32x4{0.f,0.f,0.f,0.f}, 0,0,0);
                o_[dv][nq] = __builtin_amdgcn_mfma_f32_16x16x32_bf16(av[dv][1], bp[nq][1],
                                 o_[dv][nq], 0,0,0);
            }
        __builtin_amdgcn_s_setprio(0);
        __builtin_amdgcn_sched_barrier(0);

        // normalized attn_out -> proj A-frag blocks BLK(nq) (uint2 writes)
        #pragma unroll
        for (int dv=0; dv<2; ++dv) {
            const u32 chunk = (u32)lr + 16u*(u32)(2*dv + (lg>>1));
            #pragma unroll
            for (int nq=0; nq<4; ++nq) {
                const float r = rsum[nq];
                *reinterpret_cast<uint2*>(&smem[BLK(nq) + swz(chunk)*8 + 4*(lg&1)]) =
                    make_uint2(cvtpk(o_[dv][nq][0]*r, o_[dv][nq][1]*r),
                               cvtpk(o_[dv][nq][2]*r, o_[dv][nq][3]*r));
            }
        }
        #undef BLK
    }
    __syncthreads();

    // ---- Phase 4: proj GEMM [64x192]@[192x192] + bias + residual (R12) ----
    {
        f32x4 a2[4][2];
        #pragma unroll
        for (int mi=0; mi<4; ++mi)
            #pragma unroll
            for (int ni=0; ni<2; ++ni) a2[mi][ni] = f32x4{0.f,0.f,0.f,0.f};
        #pragma unroll
        for (int ks=0; ks<6; ++ks) {
            bf16x8 af[4], bw[2];
            #pragma unroll
            for (int mi=0; mi<4; ++mi)
                af[mi] = ldfrag(&smem[SB + (u32)((mi*6+ks)*512) + lsw*8]);
            #pragma unroll
            for (int ni=0; ni<2; ++ni)
                bw[ni] = ldfrag(&wproj_t[(wid*32 + 16*ni + lr)*192 + 32*ks + 8*lg]);
            __builtin_amdgcn_s_setprio(1);
            #pragma unroll
            for (int mi=0; mi<4; ++mi)
                #pragma unroll
                for (int ni=0; ni<2; ++ni)
                    a2[mi][ni] = __builtin_amdgcn_mfma_f32_16x16x32_bf16(af[mi], bw[ni], a2[mi][ni], 0,0,0);
            __builtin_amdgcn_s_setprio(0);
        }
        #pragma unroll
        for (int ni=0; ni<2; ++ni) {
            const int c  = wid*32 + 16*ni + lr;
            const float pb = proj_b[c];
            #pragma unroll
            for (int mi=0; mi<4; ++mi)
                #pragma unroll
                for (int rg=0; rg<4; ++rg) {
                    const int row = 16*mi + 4*lg + rg;
                    const int ty = row >> 3, tx = row & 7;
                    const int shy = (wy*8 + ty + SHIFT) & 127;
                    const int shx = (wx*8 + tx + SHIFT) & 127;
                    const size_t idx = ((size_t)((b*128 + shy)*128 + shx))*192 + c;
                    xout[idx] = xin[idx] + a2[mi][ni][rg] + pb;
                }
        }
    }
}

// ws layout (u16): [0) wqkv1_t 110592 | 110592) wproj1_t 36864 | 147456) wqkv2_t 110592 | 258048) wproj2_t 36864
__global__ void prep_weights(const float* __restrict__ qkv1, const float* __restrict__ proj1,
                             const float* __restrict__ qkv2, const float* __restrict__ proj2,
                             u16* __restrict__ ws)
{
    const int i = blockIdx.x*blockDim.x + threadIdx.x;
    if (i < 110592) {
        const int n = i / 192, k = i - n*192;
        ws[i]          = f2bf(qkv1[k*576 + n]);
        ws[147456 + i] = f2bf(qkv2[k*576 + n]);
    }
    if (i < 36864) {
        const int n = i / 192, k = i - n*192;
        ws[110592 + i] = f2bf(proj1[k*192 + n]);
        ws[258048 + i] = f2bf(proj2[k*192 + n]);
    }
}

extern "C" void kernel_launch(void* const* d_in, const int* in_sizes, int n_in,
                              void* d_out, int out_size, void* d_ws, size_t ws_size,
                              hipStream_t stream)
{
    const float* x       = (const float*)d_in[0];
    const float* ln1_g   = (const float*)d_in[1];
    const float* ln1_b   = (const float*)d_in[2];
    const float* qkv1_w  = (const float*)d_in[3];
    const float* qkv1_b  = (const float*)d_in[4];
    const float* proj1_w = (const float*)d_in[5];
    const float* proj1_b = (const float*)d_in[6];
    const float* ln2_g   = (const float*)d_in[7];
    const float* ln2_b   = (const float*)d_in[8];
    const float* qkv2_w  = (const float*)d_in[9];
    const float* qkv2_b  = (const float*)d_in[10];
    const float* proj2_w = (const float*)d_in[11];
    const float* proj2_b = (const float*)d_in[12];
    float* out = (float*)d_out;
    u16*   wsp = (u16*)d_ws;

    prep_weights<<<dim3(432), dim3(256), 0, stream>>>(qkv1_w, proj1_w, qkv2_w, proj2_w, wsp);
    swin_branch<0><<<dim3(1024), dim3(768), 0, stream>>>(x,   out, ln1_g, ln1_b,
                                                         wsp,        qkv1_b, wsp+110592, proj1_b);
    swin_branch<4><<<dim3(1024), dim3(768), 0, stream>>>(out, out, ln2_g, ln2_b,
                                                         wsp+147456, qkv2_b, wsp+258048, proj2_b);
}

// Round 19
// 262.109 us; speedup vs baseline: 1.8651x; 1.0036x over previous
//
#include <hip/hip_runtime.h>

typedef unsigned int   u32;
typedef unsigned short u16;
typedef __bf16 bf16x8 __attribute__((ext_vector_type(8)));
typedef float  f32x4  __attribute__((ext_vector_type(4)));

__device__ __forceinline__ u16 f2bf(float f) {
    u32 u = __builtin_bit_cast(u32, f);
    u += 0x7FFFu + ((u >> 16) & 1u);
    return (u16)(u >> 16);
}
// packed f32x2 -> bf16x2 (RNE), single instruction
__device__ __forceinline__ u32 cvtpk(float a, float b) {
    u32 r;
    asm("v_cvt_pk_bf16_f32 %0, %1, %2" : "=v"(r) : "v"(a), "v"(b));
    return r;
}
__device__ __forceinline__ bf16x8 ldfrag(const u16* p) {
    return __builtin_bit_cast(bf16x8, *reinterpret_cast<const uint4*>(p));
}

// bank-conflict swizzle on the 16B-chunk index (0..63): fold bits[5:3] into [2:0].
__device__ __forceinline__ u32 swz(u32 i) { return i ^ ((i >> 3) & 7u); }

// ---------------------------------------------------------------------------
// Fused Swin branch, R19 = R18 with phase 3 REORDERED to cover LDS
// write->read round-trip latency with compute (zero new instructions):
//   - bq reads issued BEFORE the K scatter (no outstanding writes on QB ->
//     those reads complete immediately in the in-order LDS pipe).
//   - P^T scatter interleaved INTO the S^T mi-loop (each mi's scatter rides
//     behind the next mi's MFMA+exp; p16 liveness 32->8 regs).
//   - V^T scatter moved between bp reads and rsum MFMAs (8 MFMAs cover the
//     V-write latency before av reads).
// Everything else identical to R18 (= R12 + setprio, best 156us/branch).
// Measured walls: >128-reg/wave => no 2nd WG (R8/R14 spill); cross-phase
// x-prefetch breaks residual L2 locality (R9/R13/R15 FETCH 2.5-3x); setprio
// null (R18); swapped-P4 float4 epilogue slower (R16/R17).
// WG = 768 threads = 12 waves = TWO windows (balanced 3 waves/SIMD).
// Per-window LDS (u16, base=win*24576): [0,12288) yln 24 frag blocks
// (phase 3: wave w's blocks {s*6+w} = K scratch -> P(ks=1) -> O^T);
// [12288,24576) qreg 4 blocks/head (Q -> P(ks=0) -> V^T).
// ---------------------------------------------------------------------------
template<int SHIFT>
__global__ __launch_bounds__(768) void swin_branch(
    const float* __restrict__ xin, float* __restrict__ xout,
    const float* __restrict__ ln_g, const float* __restrict__ ln_b,
    const u16*   __restrict__ wqkv_t,  // [576][192] bf16 (pre-transposed)
    const float* __restrict__ qkv_b,   // [576]
    const u16*   __restrict__ wproj_t, // [192][192] bf16 (pre-transposed)
    const float* __restrict__ proj_b)  // [192]
{
    __shared__ __align__(16) u16 smem[49152];
    __shared__ float red1[2][6][64];
    __shared__ float red2[2][6][64];
    constexpr u32 QOFF = 12288;
    constexpr float QSC = 0.17677669529663689f * 1.4426950408889634f; // 1/sqrt(32)*log2(e)

    const int tid  = threadIdx.x;
    const int win  = (tid >= 384) ? 1 : 0;
    const int lt   = tid - win*384;
    const int wid  = lt >> 6;               // wave == head
    const int lane = lt & 63;
    const int lr   = lane & 15;
    const int lg   = lane >> 4;
    const u32 lsw  = swz((u32)lane);
    const u32 SB   = (u32)win * 24576u;

    const int Wid = blockIdx.x*2 + win;     // b*256 + wy*16 + wx
    const int b   = Wid >> 8;
    const int wy  = (Wid >> 4) & 15;
    const int wx  = Wid & 15;

    // ---- Phase 1: gather window (rolled), LayerNorm -> yln (frag layout) ----
    {
        const int ty = lane >> 3, tx = lane & 7;
        const int shy = (wy*8 + ty + SHIFT) & 127;
        const int shx = (wx*8 + tx + SHIFT) & 127;
        const float* xp = xin + ((size_t)((b*128 + shy)*128 + shx))*192 + wid*32;
        float xv[32];
        float s1 = 0.f, s2 = 0.f;
        #pragma unroll
        for (int j = 0; j < 8; ++j) {
            float4 v = reinterpret_cast<const float4*>(xp)[j];
            xv[j*4+0]=v.x; xv[j*4+1]=v.y; xv[j*4+2]=v.z; xv[j*4+3]=v.w;
            s1 += v.x+v.y+v.z+v.w;
            s2 += v.x*v.x + v.y*v.y + v.z*v.z + v.w*v.w;
        }
        red1[win][wid][lane] = s1; red2[win][wid][lane] = s2;
        __syncthreads();
        float a1 = 0.f, a2 = 0.f;
        #pragma unroll
        for (int w = 0; w < 6; ++w) { a1 += red1[win][w][lane]; a2 += red2[win][w][lane]; }
        const float mu = a1 * (1.f/192.f);
        const float rs = rsqrtf(a2 * (1.f/192.f) - mu*mu + 1e-5f);
        const float* gp = ln_g + wid*32;
        const float* bp = ln_b + wid*32;
        const u32 yblk = SB + (u32)((lg*6 + wid)*512);
        #pragma unroll
        for (int cc8 = 0; cc8 < 4; ++cc8) {
            u32 pk[4];
            #pragma unroll
            for (int q = 0; q < 4; ++q) {
                int j = cc8*8 + q*2;
                float y0 = (xv[j]   - mu)*rs*gp[j]   + bp[j];
                float y1 = (xv[j+1] - mu)*rs*gp[j+1] + bp[j+1];
                pk[q] = cvtpk(y0, y1);
            }
            *reinterpret_cast<uint4*>(&smem[yblk + swz((u32)(lr + 16*cc8))*8]) =
                make_uint4(pk[0],pk[1],pk[2],pk[3]);
        }
    }
    __syncthreads();

    // ---- Phase 2: QKV GEMM ----
    uint2 kpk[4][2];     // K^T packed bf16 (crosses barrier in regs)
    uint2 vpk[4][2];     // V  packed bf16 (crosses barrier in regs)
    {
        // pass 1 (SWAPPED): Q^T,K^T = mfma(W-frag, yln-frag)
        // D: lane holds X^T[d=16t+4lg+rg][token=16mi+lr]
        {
            f32x4 acc[4][4];
            #pragma unroll
            for (int mi=0; mi<4; ++mi)
                #pragma unroll
                for (int t=0; t<4; ++t) acc[mi][t] = f32x4{0.f,0.f,0.f,0.f};
            #pragma unroll
            for (int ks=0; ks<6; ++ks) {
                bf16x8 af[4];
                #pragma unroll
                for (int mi=0; mi<4; ++mi)
                    af[mi] = ldfrag(&smem[SB + (u32)((mi*6+ks)*512) + lsw*8]);
                bf16x8 bw[4];
                #pragma unroll
                for (int t=0; t<4; ++t)
                    bw[t] = ldfrag(&wqkv_t[((t>>1)*192 + wid*32 + (t&1)*16 + lr)*192 + 32*ks + 8*lg]);
                __builtin_amdgcn_s_setprio(1);
                #pragma unroll
                for (int mi=0; mi<4; ++mi)
                    #pragma unroll
                    for (int t=0; t<4; ++t)
                        acc[mi][t] = __builtin_amdgcn_mfma_f32_16x16x32_bf16(bw[t], af[mi], acc[mi][t], 0,0,0);
                __builtin_amdgcn_s_setprio(0);
            }
            // Q: bias + QSC scale -> qreg as B-frag (uint2 writes, wave-private)
            #pragma unroll
            for (int t=0; t<2; ++t) {
                const float4 b4 = *reinterpret_cast<const float4*>(&qkv_b[wid*32 + t*16 + 4*lg]);
                const u32 chunk = (u32)lr + 16u*(u32)(2*t + (lg>>1));
                #pragma unroll
                for (int mi=0; mi<4; ++mi) {
                    float v0 = (acc[mi][t][0] + b4.x) * QSC;
                    float v1 = (acc[mi][t][1] + b4.y) * QSC;
                    float v2 = (acc[mi][t][2] + b4.z) * QSC;
                    float v3 = (acc[mi][t][3] + b4.w) * QSC;
                    *reinterpret_cast<uint2*>(
                        &smem[SB + QOFF + (u32)(wid*2048) + mi*512 + swz(chunk)*8 + 4*(lg&1)]) =
                        make_uint2(cvtpk(v0,v1), cvtpk(v2,v3));
                }
            }
            // K: bias -> kpk regs
            #pragma unroll
            for (int t2=0; t2<2; ++t2) {
                const float4 b4 = *reinterpret_cast<const float4*>(&qkv_b[192 + wid*32 + t2*16 + 4*lg]);
                #pragma unroll
                for (int mi=0; mi<4; ++mi)
                    kpk[mi][t2] = make_uint2(
                        cvtpk(acc[mi][2+t2][0] + b4.x, acc[mi][2+t2][1] + b4.y),
                        cvtpk(acc[mi][2+t2][2] + b4.z, acc[mi][2+t2][3] + b4.w));
            }
        }
        // pass 2 (unswapped): V = mfma(yln, Wv); lane holds V[token=16mi+4lg+rg][d=16tv+lr]
        {
            f32x4 acc[4][2];
            #pragma unroll
            for (int mi=0; mi<4; ++mi)
                #pragma unroll
                for (int t=0; t<2; ++t) acc[mi][t] = f32x4{0.f,0.f,0.f,0.f};
            #pragma unroll
            for (int ks=0; ks<6; ++ks) {
                bf16x8 af[4];
                #pragma unroll
                for (int mi=0; mi<4; ++mi)
                    af[mi] = ldfrag(&smem[SB + (u32)((mi*6+ks)*512) + lsw*8]);
                bf16x8 bw[2];
                #pragma unroll
                for (int t=0; t<2; ++t)
                    bw[t] = ldfrag(&wqkv_t[(384 + wid*32 + t*16 + lr)*192 + 32*ks + 8*lg]);
                __builtin_amdgcn_s_setprio(1);
                #pragma unroll
                for (int mi=0; mi<4; ++mi)
                    #pragma unroll
                    for (int t=0; t<2; ++t)
                        acc[mi][t] = __builtin_amdgcn_mfma_f32_16x16x32_bf16(af[mi], bw[t], acc[mi][t], 0,0,0);
                __builtin_amdgcn_s_setprio(0);
            }
            #pragma unroll
            for (int tv=0; tv<2; ++tv) {
                const float bias = qkv_b[384 + wid*32 + tv*16 + lr];
                #pragma unroll
                for (int mi=0; mi<4; ++mi)
                    vpk[mi][tv] = make_uint2(
                        cvtpk(acc[mi][tv][0] + bias, acc[mi][tv][1] + bias),
                        cvtpk(acc[mi][tv][2] + bias, acc[mi][tv][3] + bias));
            }
        }
    }
    __syncthreads();   // yln reads done -> wave w's blocks {s*6+w} become scratch

    // ---- Phase 3: attention (all-swapped, wave-local; reordered for overlap) ----
    float rsum[4];       // per q-col tile nq (q is lane-local on lr)
    f32x4 o_[2][4];      // O^T [dv][nq]
    {
        const u32 W  = SB + (u32)(wid*512);
        const u32 QB = SB + QOFF + (u32)(wid*2048);
        #define BLK(s) ((u32)(s)*3072u + W)

        // bq reads FIRST (QB has no outstanding writes -> completes immediately)
        bf16x8 bq[4];
        #pragma unroll
        for (int nq=0; nq<4; ++nq) bq[nq] = ldfrag(&smem[QB + nq*512 + lsw*8]);

        // K scatter (A-frag): block mi, chunk = lr + 16*(2t2+(lg>>1))
        #pragma unroll
        for (int t2=0; t2<2; ++t2) {
            const u32 chunk = (u32)lr + 16u*(u32)(2*t2 + (lg>>1));
            #pragma unroll
            for (int mi=0; mi<4; ++mi)
                *reinterpret_cast<uint2*>(
                    &smem[BLK(mi) + swz(chunk)*8 + 4*(lg&1)]) = kpk[mi][t2];
        }
        bf16x8 ak[4];
        #pragma unroll
        for (int mi=0; mi<4; ++mi) ak[mi] = ldfrag(&smem[BLK(mi) + lsw*8]);
        __builtin_amdgcn_sched_barrier(0);

        // q-col classes (per nq; col qt = 16nq+lr)
        int qcl[4];
        if constexpr (SHIFT > 0) {
            #pragma unroll
            for (int nq=0; nq<4; ++nq) {
                const int qt = 16*nq + lr;
                const int hu = wy*8 + (qt>>3);
                const int wu = wx*8 + (qt&7);
                qcl[nq] = ((hu >= 124) ? 2 : (hu >= 120 ? 1 : 0))*3
                        + ((wu >= 124) ? 2 : (wu >= 120 ? 1 : 0));
            }
        }

        // S^T = mfma(K,Q); exp2; zero-mask; pack; SCATTER INTERLEAVED per mi
        // (each mi's P writes ride behind the next mi's MFMA+exp work)
        #pragma unroll
        for (int mi=0; mi<4; ++mi) {
            f32x4 sr[4];
            __builtin_amdgcn_s_setprio(1);
            #pragma unroll
            for (int nq=0; nq<4; ++nq)
                sr[nq] = __builtin_amdgcn_mfma_f32_16x16x32_bf16(ak[mi], bq[nq],
                             f32x4{0.f,0.f,0.f,0.f}, 0,0,0);
            __builtin_amdgcn_s_setprio(0);
            #pragma unroll
            for (int rg=0; rg<4; ++rg) {
                int kcl = 0;
                if constexpr (SHIFT > 0) {
                    const int kt = 16*mi + 4*lg + rg;
                    const int hu = wy*8 + (kt>>3);
                    const int wu = wx*8 + (kt&7);
                    kcl = ((hu >= 124) ? 2 : (hu >= 120 ? 1 : 0))*3
                        + ((wu >= 124) ? 2 : (wu >= 120 ? 1 : 0));
                }
                #pragma unroll
                for (int nq=0; nq<4; ++nq) {
                    float e = exp2f(sr[nq][rg]);
                    if constexpr (SHIFT > 0)
                        e = (kcl == qcl[nq]) ? e : 0.f;
                    sr[nq][rg] = e;
                }
            }
            // P^T scatter (B-frag): block(nq, ks=mi>>1): ks0 -> QB(nq), ks1 -> BLK(nq)
            const u32 chunk = (u32)lr + 16u*(u32)(2*(mi&1) + (lg>>1));
            #pragma unroll
            for (int nq=0; nq<4; ++nq) {
                const u32 base = (mi >> 1) ? BLK(nq) : (QB + nq*512);
                *reinterpret_cast<uint2*>(&smem[base + swz(chunk)*8 + 4*(lg&1)]) =
                    make_uint2(cvtpk(sr[nq][0], sr[nq][1]),
                               cvtpk(sr[nq][2], sr[nq][3]));
            }
        }
        __builtin_amdgcn_sched_barrier(0);

        bf16x8 bp[4][2];
        #pragma unroll
        for (int nq=0; nq<4; ++nq) {
            bp[nq][0] = ldfrag(&smem[QB + nq*512 + lsw*8]);
            bp[nq][1] = ldfrag(&smem[BLK(nq) + lsw*8]);
        }

        // V^T scatter (A-frag) into QB blocks, issued right after bp reads
        // (in-order LDS: reads executed before these writes; the rsum MFMAs
        // below then cover the V-write latency before av reads)
        #pragma unroll
        for (int mi=0; mi<4; ++mi) {
            const u32 chunk = (u32)lr + 16u*(u32)(2*(mi&1) + (lg>>1));
            #pragma unroll
            for (int tv=0; tv<2; ++tv)
                *reinterpret_cast<uint2*>(
                    &smem[QB + (u32)((2*tv + (mi>>1))*512) + swz(chunk)*8 + 4*(lg&1)]) = vpk[mi][tv];
        }
        __builtin_amdgcn_sched_barrier(0);

        // row sums per q-col via ones-MFMA on P^T B-frags
        bf16x8 aones;
        {
            const u32 one2 = 0x3F803F80u;
            aones = __builtin_bit_cast(bf16x8, make_uint4(one2, one2, one2, one2));
        }
        #pragma unroll
        for (int nq=0; nq<4; ++nq) {
            f32x4 racc = __builtin_amdgcn_mfma_f32_16x16x32_bf16(aones, bp[nq][0],
                             f32x4{0.f,0.f,0.f,0.f}, 0,0,0);
            racc = __builtin_amdgcn_mfma_f32_16x16x32_bf16(aones, bp[nq][1], racc, 0,0,0);
            rsum[nq] = __builtin_amdgcn_rcpf(racc[0]);
        }

        bf16x8 av[2][2];
        #pragma unroll
        for (int dv=0; dv<2; ++dv)
            #pragma unroll
            for (int ks=0; ks<2; ++ks)
                av[dv][ks] = ldfrag(&smem[QB + (u32)((2*dv + ks)*512) + lsw*8]);
        __builtin_amdgcn_sched_barrier(0);

        // O^T = V^T * P^T
        __builtin_amdgcn_s_setprio(1);
        #pragma unroll
        for (int dv=0; dv<2; ++dv)
            #pragma unroll
            for (int nq=0; nq<4; ++nq) {
                o_[dv][nq] = __builtin_amdgcn_mfma_f32_16x16x32_bf16(av[dv][0], bp[nq][0],
                                 f32x4{0.f,0.f,0.f,0.f}, 0,0,0);
                o_[dv][nq] = __builtin_amdgcn_mfma_f32_16x16x32_bf16(av[dv][1], bp[nq][1],
                                 o_[dv][nq], 0,0,0);
            }
        __builtin_amdgcn_s_setprio(0);
        __builtin_amdgcn_sched_barrier(0);

        // normalized attn_out -> proj A-frag blocks BLK(nq) (uint2 writes)
        #pragma unroll
        for (int dv=0; dv<2; ++dv) {
            const u32 chunk = (u32)lr + 16u*(u32)(2*dv + (lg>>1));
            #pragma unroll
            for (int nq=0; nq<4; ++nq) {
                const float r = rsum[nq];
                *reinterpret_cast<uint2*>(&smem[BLK(nq) + swz(chunk)*8 + 4*(lg&1)]) =
                    make_uint2(cvtpk(o_[dv][nq][0]*r, o_[dv][nq][1]*r),
                               cvtpk(o_[dv][nq][2]*r, o_[dv][nq][3]*r));
            }
        }
        #undef BLK
    }
    __syncthreads();

    // ---- Phase 4: proj GEMM [64x192]@[192x192] + bias + residual (R12) ----
    {
        f32x4 a2[4][2];
        #pragma unroll
        for (int mi=0; mi<4; ++mi)
            #pragma unroll
            for (int ni=0; ni<2; ++ni) a2[mi][ni] = f32x4{0.f,0.f,0.f,0.f};
        #pragma unroll
        for (int ks=0; ks<6; ++ks) {
            bf16x8 af[4], bw[2];
            #pragma unroll
            for (int mi=0; mi<4; ++mi)
                af[mi] = ldfrag(&smem[SB + (u32)((mi*6+ks)*512) + lsw*8]);
            #pragma unroll
            for (int ni=0; ni<2; ++ni)
                bw[ni] = ldfrag(&wproj_t[(wid*32 + 16*ni + lr)*192 + 32*ks + 8*lg]);
            __builtin_amdgcn_s_setprio(1);
            #pragma unroll
            for (int mi=0; mi<4; ++mi)
                #pragma unroll
                for (int ni=0; ni<2; ++ni)
                    a2[mi][ni] = __builtin_amdgcn_mfma_f32_16x16x32_bf16(af[mi], bw[ni], a2[mi][ni], 0,0,0);
            __builtin_amdgcn_s_setprio(0);
        }
        #pragma unroll
        for (int ni=0; ni<2; ++ni) {
            const int c  = wid*32 + 16*ni + lr;
            const float pb = proj_b[c];
            #pragma unroll
            for (int mi=0; mi<4; ++mi)
                #pragma unroll
                for (int rg=0; rg<4; ++rg) {
                    const int row = 16*mi + 4*lg + rg;
                    const int ty = row >> 3, tx = row & 7;
                    const int shy = (wy*8 + ty + SHIFT) & 127;
                    const int shx = (wx*8 + tx + SHIFT) & 127;
                    const size_t idx = ((size_t)((b*128 + shy)*128 + shx))*192 + c;
                    xout[idx] = xin[idx] + a2[mi][ni][rg] + pb;
                }
        }
    }
}

// ws layout (u16): [0) wqkv1_t 110592 | 110592) wproj1_t 36864 | 147456) wqkv2_t 110592 | 258048) wproj2_t 36864
__global__ void prep_weights(const float* __restrict__ qkv1, const float* __restrict__ proj1,
                             const float* __restrict__ qkv2, const float* __restrict__ proj2,
                             u16* __restrict__ ws)
{
    const int i = blockIdx.x*blockDim.x + threadIdx.x;
    if (i < 110592) {
        const int n = i / 192, k = i - n*192;
        ws[i]          = f2bf(qkv1[k*576 + n]);
        ws[147456 + i] = f2bf(qkv2[k*576 + n]);
    }
    if (i < 36864) {
        const int n = i / 192, k = i - n*192;
        ws[110592 + i] = f2bf(proj1[k*192 + n]);
        ws[258048 + i] = f2bf(proj2[k*192 + n]);
    }
}

extern "C" void kernel_launch(void* const* d_in, const int* in_sizes, int n_in,
                              void* d_out, int out_size, void* d_ws, size_t ws_size,
                              hipStream_t stream)
{
    const float* x       = (const float*)d_in[0];
    const float* ln1_g   = (const float*)d_in[1];
    const float* ln1_b   = (const float*)d_in[2];
    const float* qkv1_w  = (const float*)d_in[3];
    const float* qkv1_b  = (const float*)d_in[4];
    const float* proj1_w = (const float*)d_in[5];
    const float* proj1_b = (const float*)d_in[6];
    const float* ln2_g   = (const float*)d_in[7];
    const float* ln2_b   = (const float*)d_in[8];
    const float* qkv2_w  = (const float*)d_in[9];
    const float* qkv2_b  = (const float*)d_in[10];
    const float* proj2_w = (const float*)d_in[11];
    const float* proj2_b = (const float*)d_in[12];
    float* out = (float*)d_out;
    u16*   wsp = (u16*)d_ws;

    prep_weights<<<dim3(432), dim3(256), 0, stream>>>(qkv1_w, proj1_w, qkv2_w, proj2_w, wsp);
    swin_branch<0><<<dim3(1024), dim3(768), 0, stream>>>(x,   out, ln1_g, ln1_b,
                                                         wsp,        qkv1_b, wsp+110592, proj1_b);
    swin_branch<4><<<dim3(1024), dim3(768), 0, stream>>>(out, out, ln2_g, ln2_b,
                                                         wsp+147456, qkv2_b, wsp+258048, proj2_b);
}